// Round 6
// baseline (7656.023 us; speedup 1.0000x reference)
//
#include <hip/hip_runtime.h>
#include <hip/hip_bf16.h>

#define T_STEPS 256
#define BATCH   64
#define HID     512
#define NWG     256   // 4 batch-groups x 64 unit-groups
#define NTHR    256   // 4 waves

typedef float f32x4 __attribute__((ext_vector_type(4)));
typedef short bf16x8 __attribute__((ext_vector_type(8)));
typedef unsigned long long u64;

// LDS layout (dynamic shared, 1 WG/CU)
#define W0OFF   0u        // [32][1024] bf16, swizzled   (layer0)
#define W1OFF   65536u    // [32][1024] bf16, swizzled   (layer1)
#define WSTOFF  131072u   // [16][512] bf16, swizzled    (w_t rows; rows 8..15 zero)
#define T1OFF   147456u   // [16][16] f32 tile exchange (wave1 -> wave0)
#define BNCOFF  148480u   // [16][8]  f32 bounce (cell lanes -> row writers)
#define EBOFF   148992u   // [8] f32 eps_b slice (wave3 -> wave0)
#define SMEM_BYTES 149024

__device__ __forceinline__ short f2b(float f) {
  __hip_bfloat16 h = __float2bfloat16(f);
  return *reinterpret_cast<short*>(&h);
}
__device__ __forceinline__ float b2f(short s) {
  __hip_bfloat16 h;
  *reinterpret_cast<short*>(&h) = s;
  return __bfloat162float(h);
}
__device__ __forceinline__ float sigf(float x) { return 1.0f / (1.0f + __expf(-x)); }
__device__ __forceinline__ float tanh_f(float x) { return 2.0f / (1.0f + __expf(-2.0f * x)) - 1.0f; }

__device__ __forceinline__ bf16x8 pack8(float4 a, float4 b) {
  bf16x8 r;
  r[0] = f2b(a.x); r[1] = f2b(a.y); r[2] = f2b(a.z); r[3] = f2b(a.w);
  r[4] = f2b(b.x); r[5] = f2b(b.y); r[6] = f2b(b.z); r[7] = f2b(b.w);
  return r;
}

// ---- cross-XCD communication: compiler-visible agent-scope atomics ----
// RELAXED AGENT atomics lower to global_load/store_dwordx2 with the sc1
// (cross-XCD coherent) bit AND are tracked by the compiler's waitcnt pass +
// register allocator — unlike inline-asm loads, pending-register spills are
// correctly fenced (the round-3/4/5 corruption class is structurally gone).
__device__ __forceinline__ void g_store16(void* p, bf16x8 v) {
  const u64* s = reinterpret_cast<const u64*>(&v);
  u64* d = reinterpret_cast<u64*>(p);
  __hip_atomic_store(d + 0, s[0], __ATOMIC_RELAXED, __HIP_MEMORY_SCOPE_AGENT);
  __hip_atomic_store(d + 1, s[1], __ATOMIC_RELAXED, __HIP_MEMORY_SCOPE_AGENT);
}
__device__ __forceinline__ bf16x8 g_load16(const void* p) {
  const u64* s = reinterpret_cast<const u64*>(p);
  union { u64 q[2]; bf16x8 v; } u;
  u.q[0] = __hip_atomic_load(s + 0, __ATOMIC_RELAXED, __HIP_MEMORY_SCOPE_AGENT);
  u.q[1] = __hip_atomic_load(s + 1, __ATOMIC_RELAXED, __HIP_MEMORY_SCOPE_AGENT);
  return u.v;
}
// load a 16-row x (8 bf16) column slice: dst[i] = 16B at p + i*64B
__device__ __forceinline__ void g_load_frag(bf16x8* dst, const unsigned short* p) {
#pragma unroll
  for (int i = 0; i < 16; ++i) dst[i] = g_load16(p + (size_t)i * 32);
}

// per-WG flag post: agent-scope RELEASE store — compiler emits the full release
// sequence (vmcnt/lgkm drain + L2 writeback + sc1 store), ordering ALL prior
// (compiler-visible) data stores before the flag. No acquire invalidates anywhere.
__device__ __forceinline__ void post_flag(unsigned int* p, unsigned int val) {
  __hip_atomic_store(p, val, __ATOMIC_RELEASE, __HIP_MEMORY_SCOPE_AGENT);
}
// all 64 lanes of the calling wave; lane i watches cohort[i]; exits when all >= target
__device__ __forceinline__ void poll_flags(const unsigned int* cohort, unsigned int target) {
  const unsigned int* p = cohort + (threadIdx.x & 63);
  for (;;) {
    unsigned int v = __hip_atomic_load(p, __ATOMIC_RELAXED, __HIP_MEMORY_SCOPE_AGENT);
    if (__all((int)(v >= target))) break;
    __builtin_amdgcn_s_sleep(1);
  }
  __builtin_amdgcn_sched_barrier(0);
}

// stage one layer's gate-row slice (32 rows x 1024 K) fp32 global -> bf16 LDS, XOR-swizzled
__device__ __forceinline__ void stage_weights(char* smem, unsigned int base,
                                              const float* Wih, const float* Whh,
                                              int u0, int tid) {
  for (int p = tid; p < 4096; p += NTHR) {
    const int row = p >> 7;            // 0..31  (0-7 i, 8-15 f, 16-23 g, 24-31 o)
    const int col = (p & 127) * 8;     // 0..1016
    const int gate = row >> 3;
    const int grow = gate * 512 + u0 + (row & 7);
    const float* src = (col < 512) ? (Wih + (size_t)grow * HID + col)
                                   : (Whh + (size_t)grow * HID + (col - 512));
    float4 v0 = *(const float4*)src;
    float4 v1 = *(const float4*)(src + 4);
    unsigned int byte = base + (unsigned int)row * 2048u + (unsigned int)col * 2u;
    byte ^= (unsigned int)(row & 7) << 4;
    *(bf16x8*)(smem + byte) = pack8(v0, v1);
  }
}

// one K=512 product into two interleaved accumulators (two independent chains)
__device__ __forceinline__ void mm_half(const char* smem, const bf16x8* a, unsigned int wOff,
                                        int brow, int colHalf, int koff, f32x4& A0, f32x4& A1) {
  const unsigned int bb = wOff + (unsigned int)brow * 2048u + (unsigned int)colHalf * 2u;
  const unsigned int sw = (unsigned int)(brow & 7) << 4;
#pragma unroll
  for (int ks = 0; ks < 16; ++ks) {
    bf16x8 b = *(const bf16x8*)(smem + ((bb + (unsigned int)((ks * 32 + koff) * 2)) ^ sw));
    if (ks & 1)
      A1 = __builtin_amdgcn_mfma_f32_16x16x32_bf16(a[ks], b, A1, 0, 0, 0);
    else
      A0 = __builtin_amdgcn_mfma_f32_16x16x32_bf16(a[ks], b, A0, 0, 0, 0);
  }
}

// wave0: acc = tile0 [i|f]; T1 in LDS = tile1 [g|o]; produces h (hv) and updates c (cst)
__device__ __forceinline__ void cell_update(char* smem, f32x4 acc, float bt0, float bgb,
                                            float bob, float* cst, float* hv, int lane) {
#pragma unroll
  for (int j = 0; j < 4; ++j) acc[j] += bt0;   // own-column bias (i or f)
  float part[4];
#pragma unroll
  for (int j = 0; j < 4; ++j) part[j] = __shfl_xor(acc[j], 8);
  const float* T1 = (const float*)(smem + T1OFF);
  const int cs = lane & 7;
  const int rb = (lane >> 4) * 4;
#pragma unroll
  for (int j = 0; j < 4; ++j) {
    const float iv = acc[j];                       // valid for lanes col<8
    const float fv = part[j];
    const float gv = T1[(rb + j) * 16 + cs] + bgb;
    const float ov = T1[(rb + j) * 16 + cs + 8] + bob;
    const float cn = sigf(fv) * cst[j] + sigf(iv) * tanh_f(gv);
    cst[j] = cn;
    hv[j] = sigf(ov) * tanh_f(cn);
  }
}

extern "C" __global__ void __launch_bounds__(NTHR, 1)
dlstm_kernel(const float* __restrict__ init_h, const float* __restrict__ init_c,
             const float* __restrict__ eps_w, const float* __restrict__ eps_b,
             const float* __restrict__ W_ih0, const float* __restrict__ W_hh0,
             const float* __restrict__ b_ih0, const float* __restrict__ b_hh0,
             const float* __restrict__ W_ih1, const float* __restrict__ W_hh1,
             const float* __restrict__ b_ih1, const float* __restrict__ b_hh1,
             const float* __restrict__ w_mu, const float* __restrict__ w_log_var,
             const float* __restrict__ b_mu, const float* __restrict__ b_log_var,
             float* __restrict__ out, unsigned int* __restrict__ flags,
             unsigned short* __restrict__ xbuf, unsigned short* __restrict__ h0buf,
             unsigned short* __restrict__ h1buf) {
  extern __shared__ char smem[];
  const int tid = threadIdx.x;
  const int bid = blockIdx.x;
  const int bg = bid & 3;            // batch group (cohort): rows [bg*16, bg*16+16)
  const int u  = bid >> 2;           // unit-slice index 0..63
  const int u0 = u * 8;
  const int wave = tid >> 6;
  const int lane = tid & 63;
  const int col = lane & 15;
  const int cs = lane & 7;
  const int rb = (lane >> 4) * 4;
  const int koff = (lane >> 4) * 8;
  const bool is_act = col < 8;
  const size_t BH = (size_t)BATCH * HID;
  unsigned int* cohort = flags + bg * 256;   // 1KB-strided cohorts (64 WGs each)
  unsigned int* myflag = cohort + u;
  const int arow = bg * 16 + col;
  const int brow = wave * 16 + col;

  // ---------------- one-time init ----------------
  stage_weights(smem, W0OFF, W_ih0, W_hh0, u0, tid);
  stage_weights(smem, W1OFF, W_ih1, W_hh1, u0, tid);
  {  // zero wstage pad rows 8..15 (MFMA N-tile is 16 wide, only 8 real rows)
    bf16x8 z = {0, 0, 0, 0, 0, 0, 0, 0};
    for (int p = tid; p < 512; p += NTHR) {
      const int row = 8 + (p >> 6);
      const int c8 = (p & 63) * 8;
      unsigned int byte = WSTOFF + (unsigned int)row * 1024u + (unsigned int)c8 * 2u;
      byte ^= (unsigned int)(row & 7) << 4;
      *(bf16x8*)(smem + byte) = z;
    }
  }
  // wave0 per-lane constants + states
  float bt0_l0 = 0, bt0_l1 = 0, bgb0 = 0, bob0 = 0, bgb1 = 0, bob1 = 0, bmu_l = 0, bsg_l = 0;
  float c0r[4] = {0, 0, 0, 0}, c1r[4] = {0, 0, 0, 0};
  if (wave == 0) {
    const int ofs = (col < 8) ? 0 : 512;
    const int un = u0 + cs;
    bt0_l0 = b_ih0[ofs + un] + b_hh0[ofs + un];
    bt0_l1 = b_ih1[ofs + un] + b_hh1[ofs + un];
    bgb0 = b_ih0[1024 + un] + b_hh0[1024 + un];
    bob0 = b_ih0[1536 + un] + b_hh0[1536 + un];
    bgb1 = b_ih1[1024 + un] + b_hh1[1024 + un];
    bob1 = b_ih1[1536 + un] + b_hh1[1536 + un];
    bmu_l = b_mu[un];
    bsg_l = __expf(0.5f * b_log_var[un]);
    if (is_act) {
#pragma unroll
      for (int j = 0; j < 4; ++j) {
        c0r[j] = init_c[(size_t)(0 * BATCH + bg * 16 + rb + j) * HID + un];
        c1r[j] = init_c[(size_t)(1 * BATCH + bg * 16 + rb + j) * HID + un];
      }
    }
    if (lane < 16) {  // write this WG's tile of the parity-0 state buffers
      const int row = bg * 16 + lane;
      const float* s0 = init_h + (size_t)row * HID + u0;
      const float* s1 = init_h + (size_t)(BATCH + row) * HID + u0;
      g_store16(h0buf + (size_t)row * HID + u0,
                pack8(*(const float4*)s0, *(const float4*)(s0 + 4)));
      g_store16(h1buf + (size_t)row * HID + u0,
                pack8(*(const float4*)s1, *(const float4*)(s1 + 4)));
      bf16x8 z = {0, 0, 0, 0, 0, 0, 0, 0};
      g_store16(xbuf + (size_t)row * HID + u0, z);  // x_0 = 0
    }
    if (lane == 0) post_flag(myflag, 1u);   // RELEASE orders the stores above
  }
  __syncthreads();  // SYNC0: LDS weight staging complete

  // ---------------- time loop ----------------
#pragma unroll 1
  for (int t = 0; t < T_STEPS; ++t) {
    const int pp = t & 1;
    const unsigned int tb = 3u * (unsigned int)t;

    // waves 2/3: build w_t into LDS (plain cached loads — read-only inputs,
    // off the critical path), stage eps_b[t] for wave0
    if (wave >= 2) {
      const int q = tid - 128;       // 0..127
      const int erow = q >> 4;       // 0..7
      const int ecb = (q & 15) * 32; // 0..480
      const float* pm = w_mu + (size_t)(u0 + erow) * HID + ecb;
      const float* pv = w_log_var + (size_t)(u0 + erow) * HID + ecb;
      const float* pe = eps_w + (size_t)t * HID * HID + (size_t)(u0 + erow) * HID + ecb;
      const unsigned int sw = (unsigned int)erow << 4;
      const unsigned int b0 = WSTOFF + (unsigned int)erow * 1024u + (unsigned int)ecb * 2u;
#pragma unroll
      for (int c = 0; c < 4; ++c) {
        bf16x8 v;
#pragma unroll
        for (int qq = 0; qq < 8; ++qq) {
          const int idx = c * 8 + qq;
          v[qq] = f2b(fmaf(__expf(0.5f * pv[idx]), pe[idx], pm[idx]));
        }
        *(bf16x8*)(smem + ((b0 + (unsigned int)c * 16u) ^ sw)) = v;
      }
      if (wave == 3 && lane < 8)
        ((float*)(smem + EBOFF))[lane] = eps_b[(size_t)t * HID + u0 + lane];
    }

    // ============== PHASE 0: gates0 -> h0 ==============
    f32x4 g0 = {0.f, 0.f, 0.f, 0.f};
    if (wave < 2) {
      poll_flags(cohort, tb + 1u);
      bf16x8 sa[16], fa[16];
      g_load_frag(sa, h0buf + (size_t)pp * BH + (size_t)arow * HID + koff);
      g_load_frag(fa, xbuf + (size_t)pp * BH + (size_t)arow * HID + koff);
      f32x4 A0 = {0, 0, 0, 0}, A1 = {0, 0, 0, 0};
      mm_half(smem, sa, W0OFF, brow, 512, koff, A0, A1);   // W_hh0 * h0(t-1)
      mm_half(smem, fa, W0OFF, brow, 0, koff, A0, A1);     // W_ih0 * x(t)
      g0 = A0 + A1;
      if (wave == 1) {
        float* T1 = (float*)(smem + T1OFF);
#pragma unroll
        for (int j = 0; j < 4; ++j) T1[(rb + j) * 16 + col] = g0[j];
      }
    }
    __syncthreads();  // SYNC1
    if (wave == 0) {
      float hv[4];
      cell_update(smem, g0, bt0_l0, bgb0, bob0, c0r, hv, lane);
      float* BNC = (float*)(smem + BNCOFF);
      if (is_act) {
#pragma unroll
        for (int j = 0; j < 4; ++j) BNC[(rb + j) * 8 + cs] = hv[j];
      }
      asm volatile("s_waitcnt lgkmcnt(0)" ::: "memory");
      if (lane < 16) {
        const int row = bg * 16 + lane;
        float4 v0 = *(float4*)(BNC + lane * 8);
        float4 v1 = *(float4*)(BNC + lane * 8 + 4);
        g_store16(h0buf + (size_t)(pp ^ 1) * BH + (size_t)row * HID + u0, pack8(v0, v1));
      }
      if (lane == 0) post_flag(myflag, tb + 2u);  // RELEASE
    }

    // ============== PHASE 1: gates1 -> h1 (+ d_out) ==============
    f32x4 g1 = {0.f, 0.f, 0.f, 0.f};
    if (wave < 2) {
      poll_flags(cohort, tb + 2u);
      bf16x8 sa[16], fa[16];
      g_load_frag(sa, h1buf + (size_t)pp * 2 * BH + (size_t)arow * HID + koff);
      g_load_frag(fa, h0buf + (size_t)(pp ^ 1) * BH + (size_t)arow * HID + koff);
      f32x4 A0 = {0, 0, 0, 0}, A1 = {0, 0, 0, 0};
      mm_half(smem, sa, W1OFF, brow, 512, koff, A0, A1);   // W_hh1 * h1(t-1)
      mm_half(smem, fa, W1OFF, brow, 0, koff, A0, A1);     // W_ih1 * h0(t)
      g1 = A0 + A1;
      if (wave == 1) {
        float* T1 = (float*)(smem + T1OFF);
#pragma unroll
        for (int j = 0; j < 4; ++j) T1[(rb + j) * 16 + col] = g1[j];
      }
    }
    __syncthreads();  // SYNC2
    if (wave == 0) {
      float hv[4];
      cell_update(smem, g1, bt0_l1, bgb1, bob1, c1r, hv, lane);
      float* BNC = (float*)(smem + BNCOFF);
      if (is_act) {
#pragma unroll
        for (int j = 0; j < 4; ++j) BNC[(rb + j) * 8 + cs] = hv[j];
      }
      asm volatile("s_waitcnt lgkmcnt(0)" ::: "memory");
      float4 v0 = {0, 0, 0, 0}, v1 = {0, 0, 0, 0};
      if (lane < 16) {
        const int row = bg * 16 + lane;
        v0 = *(float4*)(BNC + lane * 8);
        v1 = *(float4*)(BNC + lane * 8 + 4);
        bf16x8 hi = pack8(v0, v1);
        unsigned short* base = h1buf + (size_t)(pp ^ 1) * 2 * BH;
        g_store16(base + (size_t)row * HID + u0, hi);
        bf16x8 lo;  // residual for the BL matmul (w_t row norms ~5.4 amplify h1 error)
        const float* va = (const float*)&v0;
        const float* vb = (const float*)&v1;
#pragma unroll
        for (int q = 0; q < 8; ++q) {
          const float f = (q < 4) ? va[q] : vb[q - 4];
          lo[q] = f2b(f - b2f(hi[q]));
        }
        g_store16(base + BH + (size_t)row * HID + u0, lo);
      }
      if (lane == 0) post_flag(myflag, tb + 3u);  // RELEASE
      if (lane < 16) {  // d_out write AFTER the flag (off the critical path)
        const int row = bg * 16 + lane;
        float* od = out + ((size_t)t * BATCH + row) * HID + u0;
        *(float4*)od = v0;
        *(float4*)(od + 4) = v1;
      }
    }

    // ============== PHASE 2: x_{t+1} = h1 @ w_t^T + b_t ==============
    if (t + 1 < T_STEPS) {
      if (wave == 0) {
        poll_flags(cohort, tb + 3u);
        bf16x8 ahi[16], alo[16];
        const unsigned short* hb =
            h1buf + (size_t)(pp ^ 1) * 2 * BH + (size_t)arow * HID + koff;
        g_load_frag(ahi, hb);
        g_load_frag(alo, hb + BH);
        f32x4 A0 = {0, 0, 0, 0}, A1 = {0, 0, 0, 0};
        const unsigned int bb = WSTOFF + (unsigned int)col * 1024u;
        const unsigned int sw = (unsigned int)(col & 7) << 4;
#pragma unroll
        for (int ks = 0; ks < 16; ++ks) {
          bf16x8 b =
              *(const bf16x8*)(smem + ((bb + (unsigned int)((ks * 32 + koff) * 2)) ^ sw));
          A0 = __builtin_amdgcn_mfma_f32_16x16x32_bf16(ahi[ks], b, A0, 0, 0, 0);
          A1 = __builtin_amdgcn_mfma_f32_16x16x32_bf16(alo[ks], b, A1, 0, 0, 0);
        }
        const float ebv = is_act ? ((const float*)(smem + EBOFF))[cs] : 0.f;
        const float xb = bmu_l + bsg_l * ebv;
        f32x4 a2 = A0 + A1;
        float* BNC = (float*)(smem + BNCOFF);
        if (is_act) {
#pragma unroll
          for (int j = 0; j < 4; ++j) BNC[(rb + j) * 8 + cs] = a2[j] + xb;
        }
        asm volatile("s_waitcnt lgkmcnt(0)" ::: "memory");
        if (lane < 16) {
          const int row = bg * 16 + lane;
          float4 v0 = *(float4*)(BNC + lane * 8);
          float4 v1 = *(float4*)(BNC + lane * 8 + 4);
          g_store16(xbuf + (size_t)(pp ^ 1) * BH + (size_t)row * HID + u0, pack8(v0, v1));
        }
        if (lane == 0) post_flag(myflag, tb + 4u);  // RELEASE
      }
      __syncthreads();  // trailing: protect wstage/EBOFF rebuild at next loop top
    }
  }
}

extern "C" void kernel_launch(void* const* d_in, const int* in_sizes, int n_in, void* d_out,
                              int out_size, void* d_ws, size_t ws_size, hipStream_t stream) {
  const float* init_h = (const float*)d_in[1];
  const float* init_c = (const float*)d_in[2];
  const float* eps_w = (const float*)d_in[3];
  const float* eps_b = (const float*)d_in[4];
  const float* W_ih0 = (const float*)d_in[5];
  const float* W_hh0 = (const float*)d_in[6];
  const float* b_ih0 = (const float*)d_in[7];
  const float* b_hh0 = (const float*)d_in[8];
  const float* W_ih1 = (const float*)d_in[9];
  const float* W_hh1 = (const float*)d_in[10];
  const float* b_ih1 = (const float*)d_in[11];
  const float* b_hh1 = (const float*)d_in[12];
  const float* w_mu = (const float*)d_in[13];
  const float* w_log_var = (const float*)d_in[14];
  const float* b_mu = (const float*)d_in[15];
  const float* b_log_var = (const float*)d_in[16];
  float* out = (float*)d_out;

  unsigned char* ws = (unsigned char*)d_ws;
  unsigned int* flags = (unsigned int*)ws;                          // 4 cohorts * 1KB
  unsigned short* xbuf = (unsigned short*)(ws + 131072);            // 2 parity * 64*512 bf16
  unsigned short* h0buf = (unsigned short*)(ws + 262144);           // 2 parity
  unsigned short* h1buf = (unsigned short*)(ws + 393216);           // 2 parity * {hi,lo}

  hipMemsetAsync(flags, 0, 4 * 256 * sizeof(unsigned int), stream);
  hipFuncSetAttribute((const void*)dlstm_kernel, hipFuncAttributeMaxDynamicSharedMemorySize,
                      SMEM_BYTES);

  void* args[] = {(void*)&init_h, (void*)&init_c, (void*)&eps_w,  (void*)&eps_b,
                  (void*)&W_ih0,  (void*)&W_hh0,  (void*)&b_ih0,  (void*)&b_hh0,
                  (void*)&W_ih1,  (void*)&W_hh1,  (void*)&b_ih1,  (void*)&b_hh1,
                  (void*)&w_mu,   (void*)&w_log_var, (void*)&b_mu, (void*)&b_log_var,
                  (void*)&out,    (void*)&flags,     (void*)&xbuf, (void*)&h0buf,
                  (void*)&h1buf};
  hipError_t err = hipLaunchCooperativeKernel((void*)dlstm_kernel, dim3(NWG), dim3(NTHR), args,
                                              SMEM_BYTES, stream);
  if (err != hipSuccess) {
    // fallback: plain launch (256 WGs at 1/CU on 256 CUs are co-resident by capacity)
    hipLaunchKernelGGL(dlstm_kernel, dim3(NWG), dim3(NTHR), SMEM_BYTES, stream, init_h, init_c,
                       eps_w, eps_b, W_ih0, W_hh0, b_ih0, b_hh0, W_ih1, W_hh1, b_ih1, b_hh1,
                       w_mu, w_log_var, b_mu, b_log_var, out, flags, xbuf, h0buf, h1buf);
  }
}

// Round 7
// 5635.280 us; speedup vs baseline: 1.3586x; 1.3586x over previous
//
#include <hip/hip_runtime.h>
#include <hip/hip_bf16.h>

#define T_STEPS 256
#define BATCH   64
#define HID     512
#define NWG     256   // 4 batch-groups x 64 unit-groups
#define NTHR    256   // 4 waves

typedef float f32x4 __attribute__((ext_vector_type(4)));
typedef short bf16x8 __attribute__((ext_vector_type(8)));
typedef unsigned long long u64;

// LDS layout (dynamic shared, 1 WG/CU)
#define W0OFF   0u        // [32][1024] bf16, swizzled   (layer0)
#define W1OFF   65536u    // [32][1024] bf16, swizzled   (layer1)
#define WSTOFF  131072u   // [16][512] bf16, swizzled    (w_t rows; rows 8..15 zero)
#define T1OFF   147456u   // [16][16] f32 tile exchange (wave1 -> wave0)
#define BNCOFF  148480u   // [16][8]  f32 bounce (cell lanes -> row writers)
#define EBOFF   148992u   // [8] f32 eps_b slice (wave3 -> wave0)
#define SMEM_BYTES 149024

__device__ __forceinline__ short f2b(float f) {
  __hip_bfloat16 h = __float2bfloat16(f);
  return *reinterpret_cast<short*>(&h);
}
__device__ __forceinline__ float b2f(short s) {
  __hip_bfloat16 h;
  *reinterpret_cast<short*>(&h) = s;
  return __bfloat162float(h);
}
__device__ __forceinline__ float sigf(float x) { return 1.0f / (1.0f + __expf(-x)); }
__device__ __forceinline__ float tanh_f(float x) { return 2.0f / (1.0f + __expf(-2.0f * x)) - 1.0f; }

__device__ __forceinline__ bf16x8 pack8(float4 a, float4 b) {
  bf16x8 r;
  r[0] = f2b(a.x); r[1] = f2b(a.y); r[2] = f2b(a.z); r[3] = f2b(a.w);
  r[4] = f2b(b.x); r[5] = f2b(b.y); r[6] = f2b(b.z); r[7] = f2b(b.w);
  return r;
}

// ---- cross-XCD communication: compiler-visible agent-scope atomics ----
// RELAXED AGENT atomics lower to global_load/store with the cross-XCD-coherent
// cache bits AND are tracked by the compiler's waitcnt pass + register
// allocator — pending-register spills are correctly fenced (the round-3/4/5
// inline-asm corruption class is structurally gone; round 6 validated this).
__device__ __forceinline__ void g_store16(void* p, bf16x8 v) {
  const u64* s = reinterpret_cast<const u64*>(&v);
  u64* d = reinterpret_cast<u64*>(p);
  __hip_atomic_store(d + 0, s[0], __ATOMIC_RELAXED, __HIP_MEMORY_SCOPE_AGENT);
  __hip_atomic_store(d + 1, s[1], __ATOMIC_RELAXED, __HIP_MEMORY_SCOPE_AGENT);
}
__device__ __forceinline__ bf16x8 g_load16(const void* p) {
  const u64* s = reinterpret_cast<const u64*>(p);
  union { u64 q[2]; bf16x8 v; } u;
  u.q[0] = __hip_atomic_load(s + 0, __ATOMIC_RELAXED, __HIP_MEMORY_SCOPE_AGENT);
  u.q[1] = __hip_atomic_load(s + 1, __ATOMIC_RELAXED, __HIP_MEMORY_SCOPE_AGENT);
  return u.v;
}
// load a 16-row x (8 bf16) column slice: dst[i] = 16B at p + i*64B
__device__ __forceinline__ void g_load_frag(bf16x8* dst, const unsigned short* p) {
#pragma unroll
  for (int i = 0; i < 16; ++i) dst[i] = g_load16(p + (size_t)i * 32);
}

// per-WG flag post: drain this wave's write-throughs to the coherence point
// (raw s_waitcnt vmcnt(0) — no register defs, so no allocator hazard), then a
// RELAXED agent store. NO buffer_wbl2 (the RELEASE lowering's L2 writeback was
// round 6's 1.6x cost: 3 wbl2/step/WG, WRITE_SIZE 170->306 MB). The "memory"
// clobber orders the store after the drain at compile time; hardware orders it
// after the data stores' completion via the vmcnt wait.
__device__ __forceinline__ void post_flag(unsigned int* p, unsigned int val) {
  asm volatile("s_waitcnt vmcnt(0)" ::: "memory");
  __hip_atomic_store(p, val, __ATOMIC_RELAXED, __HIP_MEMORY_SCOPE_AGENT);
}
// all 64 lanes of the calling wave; lane i watches cohort[i]; exits when all >= target
__device__ __forceinline__ void poll_flags(const unsigned int* cohort, unsigned int target) {
  const unsigned int* p = cohort + (threadIdx.x & 63);
  for (;;) {
    unsigned int v = __hip_atomic_load(p, __ATOMIC_RELAXED, __HIP_MEMORY_SCOPE_AGENT);
    if (__all((int)(v >= target))) break;
    __builtin_amdgcn_s_sleep(1);
  }
  __builtin_amdgcn_sched_barrier(0);
}

// stage one layer's gate-row slice (32 rows x 1024 K) fp32 global -> bf16 LDS, XOR-swizzled
__device__ __forceinline__ void stage_weights(char* smem, unsigned int base,
                                              const float* Wih, const float* Whh,
                                              int u0, int tid) {
  for (int p = tid; p < 4096; p += NTHR) {
    const int row = p >> 7;            // 0..31  (0-7 i, 8-15 f, 16-23 g, 24-31 o)
    const int col = (p & 127) * 8;     // 0..1016
    const int gate = row >> 3;
    const int grow = gate * 512 + u0 + (row & 7);
    const float* src = (col < 512) ? (Wih + (size_t)grow * HID + col)
                                   : (Whh + (size_t)grow * HID + (col - 512));
    float4 v0 = *(const float4*)src;
    float4 v1 = *(const float4*)(src + 4);
    unsigned int byte = base + (unsigned int)row * 2048u + (unsigned int)col * 2u;
    byte ^= (unsigned int)(row & 7) << 4;
    *(bf16x8*)(smem + byte) = pack8(v0, v1);
  }
}

// one K=512 product into two interleaved accumulators (two independent chains)
__device__ __forceinline__ void mm_half(const char* smem, const bf16x8* a, unsigned int wOff,
                                        int brow, int colHalf, int koff, f32x4& A0, f32x4& A1) {
  const unsigned int bb = wOff + (unsigned int)brow * 2048u + (unsigned int)colHalf * 2u;
  const unsigned int sw = (unsigned int)(brow & 7) << 4;
#pragma unroll
  for (int ks = 0; ks < 16; ++ks) {
    bf16x8 b = *(const bf16x8*)(smem + ((bb + (unsigned int)((ks * 32 + koff) * 2)) ^ sw));
    if (ks & 1)
      A1 = __builtin_amdgcn_mfma_f32_16x16x32_bf16(a[ks], b, A1, 0, 0, 0);
    else
      A0 = __builtin_amdgcn_mfma_f32_16x16x32_bf16(a[ks], b, A0, 0, 0, 0);
  }
}

// wave0: acc = tile0 [i|f]; T1 in LDS = tile1 [g|o]; produces h (hv) and updates c (cst)
__device__ __forceinline__ void cell_update(char* smem, f32x4 acc, float bt0, float bgb,
                                            float bob, float* cst, float* hv, int lane) {
#pragma unroll
  for (int j = 0; j < 4; ++j) acc[j] += bt0;   // own-column bias (i or f)
  float part[4];
#pragma unroll
  for (int j = 0; j < 4; ++j) part[j] = __shfl_xor(acc[j], 8);
  const float* T1 = (const float*)(smem + T1OFF);
  const int cs = lane & 7;
  const int rb = (lane >> 4) * 4;
#pragma unroll
  for (int j = 0; j < 4; ++j) {
    const float iv = acc[j];                       // valid for lanes col<8
    const float fv = part[j];
    const float gv = T1[(rb + j) * 16 + cs] + bgb;
    const float ov = T1[(rb + j) * 16 + cs + 8] + bob;
    const float cn = sigf(fv) * cst[j] + sigf(iv) * tanh_f(gv);
    cst[j] = cn;
    hv[j] = sigf(ov) * tanh_f(cn);
  }
}

extern "C" __global__ void __launch_bounds__(NTHR, 1)
dlstm_kernel(const float* __restrict__ init_h, const float* __restrict__ init_c,
             const float* __restrict__ eps_w, const float* __restrict__ eps_b,
             const float* __restrict__ W_ih0, const float* __restrict__ W_hh0,
             const float* __restrict__ b_ih0, const float* __restrict__ b_hh0,
             const float* __restrict__ W_ih1, const float* __restrict__ W_hh1,
             const float* __restrict__ b_ih1, const float* __restrict__ b_hh1,
             const float* __restrict__ w_mu, const float* __restrict__ w_log_var,
             const float* __restrict__ b_mu, const float* __restrict__ b_log_var,
             float* __restrict__ out, unsigned int* __restrict__ flags,
             unsigned short* __restrict__ xbuf, unsigned short* __restrict__ h0buf,
             unsigned short* __restrict__ h1buf) {
  extern __shared__ char smem[];
  const int tid = threadIdx.x;
  const int bid = blockIdx.x;
  const int bg = bid & 3;            // batch group (cohort): rows [bg*16, bg*16+16)
  const int u  = bid >> 2;           // unit-slice index 0..63
  const int u0 = u * 8;
  const int wave = tid >> 6;
  const int lane = tid & 63;
  const int col = lane & 15;
  const int cs = lane & 7;
  const int rb = (lane >> 4) * 4;
  const int koff = (lane >> 4) * 8;
  const bool is_act = col < 8;
  const size_t BH = (size_t)BATCH * HID;
  unsigned int* cohort = flags + bg * 256;   // 1KB-strided cohorts (64 WGs each)
  unsigned int* myflag = cohort + u;
  const int arow = bg * 16 + col;
  const int brow = wave * 16 + col;

  // ---------------- one-time init ----------------
  stage_weights(smem, W0OFF, W_ih0, W_hh0, u0, tid);
  stage_weights(smem, W1OFF, W_ih1, W_hh1, u0, tid);
  {  // zero wstage pad rows 8..15 (MFMA N-tile is 16 wide, only 8 real rows)
    bf16x8 z = {0, 0, 0, 0, 0, 0, 0, 0};
    for (int p = tid; p < 512; p += NTHR) {
      const int row = 8 + (p >> 6);
      const int c8 = (p & 63) * 8;
      unsigned int byte = WSTOFF + (unsigned int)row * 1024u + (unsigned int)c8 * 2u;
      byte ^= (unsigned int)(row & 7) << 4;
      *(bf16x8*)(smem + byte) = z;
    }
  }
  // wave0 per-lane constants + states
  float bt0_l0 = 0, bt0_l1 = 0, bgb0 = 0, bob0 = 0, bgb1 = 0, bob1 = 0, bmu_l = 0, bsg_l = 0;
  float c0r[4] = {0, 0, 0, 0}, c1r[4] = {0, 0, 0, 0};
  if (wave == 0) {
    const int ofs = (col < 8) ? 0 : 512;
    const int un = u0 + cs;
    bt0_l0 = b_ih0[ofs + un] + b_hh0[ofs + un];
    bt0_l1 = b_ih1[ofs + un] + b_hh1[ofs + un];
    bgb0 = b_ih0[1024 + un] + b_hh0[1024 + un];
    bob0 = b_ih0[1536 + un] + b_hh0[1536 + un];
    bgb1 = b_ih1[1024 + un] + b_hh1[1024 + un];
    bob1 = b_ih1[1536 + un] + b_hh1[1536 + un];
    bmu_l = b_mu[un];
    bsg_l = __expf(0.5f * b_log_var[un]);
    if (is_act) {
#pragma unroll
      for (int j = 0; j < 4; ++j) {
        c0r[j] = init_c[(size_t)(0 * BATCH + bg * 16 + rb + j) * HID + un];
        c1r[j] = init_c[(size_t)(1 * BATCH + bg * 16 + rb + j) * HID + un];
      }
    }
    if (lane < 16) {  // write this WG's tile of the parity-0 state buffers
      const int row = bg * 16 + lane;
      const float* s0 = init_h + (size_t)row * HID + u0;
      const float* s1 = init_h + (size_t)(BATCH + row) * HID + u0;
      g_store16(h0buf + (size_t)row * HID + u0,
                pack8(*(const float4*)s0, *(const float4*)(s0 + 4)));
      g_store16(h1buf + (size_t)row * HID + u0,
                pack8(*(const float4*)s1, *(const float4*)(s1 + 4)));
      bf16x8 z = {0, 0, 0, 0, 0, 0, 0, 0};
      g_store16(xbuf + (size_t)row * HID + u0, z);  // x_0 = 0
    }
    if (lane == 0) post_flag(myflag, 1u);   // vmcnt-drain + relaxed post
  }
  __syncthreads();  // SYNC0: LDS weight staging complete

  // ---------------- time loop ----------------
#pragma unroll 1
  for (int t = 0; t < T_STEPS; ++t) {
    const int pp = t & 1;
    const unsigned int tb = 3u * (unsigned int)t;

    // waves 2/3: build w_t into LDS (plain cached loads — read-only inputs,
    // off the critical path), stage eps_b[t] for wave0
    if (wave >= 2) {
      const int q = tid - 128;       // 0..127
      const int erow = q >> 4;       // 0..7
      const int ecb = (q & 15) * 32; // 0..480
      const float* pm = w_mu + (size_t)(u0 + erow) * HID + ecb;
      const float* pv = w_log_var + (size_t)(u0 + erow) * HID + ecb;
      const float* pe = eps_w + (size_t)t * HID * HID + (size_t)(u0 + erow) * HID + ecb;
      const unsigned int sw = (unsigned int)erow << 4;
      const unsigned int b0 = WSTOFF + (unsigned int)erow * 1024u + (unsigned int)ecb * 2u;
#pragma unroll
      for (int c = 0; c < 4; ++c) {
        bf16x8 v;
#pragma unroll
        for (int qq = 0; qq < 8; ++qq) {
          const int idx = c * 8 + qq;
          v[qq] = f2b(fmaf(__expf(0.5f * pv[idx]), pe[idx], pm[idx]));
        }
        *(bf16x8*)(smem + ((b0 + (unsigned int)c * 16u) ^ sw)) = v;
      }
      if (wave == 3 && lane < 8)
        ((float*)(smem + EBOFF))[lane] = eps_b[(size_t)t * HID + u0 + lane];
    }

    // ============== PHASE 0: gates0 -> h0 ==============
    f32x4 g0 = {0.f, 0.f, 0.f, 0.f};
    if (wave < 2) {
      poll_flags(cohort, tb + 1u);
      bf16x8 sa[16], fa[16];
      g_load_frag(sa, h0buf + (size_t)pp * BH + (size_t)arow * HID + koff);
      g_load_frag(fa, xbuf + (size_t)pp * BH + (size_t)arow * HID + koff);
      f32x4 A0 = {0, 0, 0, 0}, A1 = {0, 0, 0, 0};
      mm_half(smem, sa, W0OFF, brow, 512, koff, A0, A1);   // W_hh0 * h0(t-1)
      mm_half(smem, fa, W0OFF, brow, 0, koff, A0, A1);     // W_ih0 * x(t)
      g0 = A0 + A1;
      if (wave == 1) {
        float* T1 = (float*)(smem + T1OFF);
#pragma unroll
        for (int j = 0; j < 4; ++j) T1[(rb + j) * 16 + col] = g0[j];
      }
    }
    __syncthreads();  // SYNC1
    if (wave == 0) {
      float hv[4];
      cell_update(smem, g0, bt0_l0, bgb0, bob0, c0r, hv, lane);
      float* BNC = (float*)(smem + BNCOFF);
      if (is_act) {
#pragma unroll
        for (int j = 0; j < 4; ++j) BNC[(rb + j) * 8 + cs] = hv[j];
      }
      asm volatile("s_waitcnt lgkmcnt(0)" ::: "memory");
      if (lane < 16) {
        const int row = bg * 16 + lane;
        float4 v0 = *(float4*)(BNC + lane * 8);
        float4 v1 = *(float4*)(BNC + lane * 8 + 4);
        g_store16(h0buf + (size_t)(pp ^ 1) * BH + (size_t)row * HID + u0, pack8(v0, v1));
      }
      if (lane == 0) post_flag(myflag, tb + 2u);
    }

    // ============== PHASE 1: gates1 -> h1 (+ d_out) ==============
    f32x4 g1 = {0.f, 0.f, 0.f, 0.f};
    if (wave < 2) {
      poll_flags(cohort, tb + 2u);
      bf16x8 sa[16], fa[16];
      g_load_frag(sa, h1buf + (size_t)pp * 2 * BH + (size_t)arow * HID + koff);
      g_load_frag(fa, h0buf + (size_t)(pp ^ 1) * BH + (size_t)arow * HID + koff);
      f32x4 A0 = {0, 0, 0, 0}, A1 = {0, 0, 0, 0};
      mm_half(smem, sa, W1OFF, brow, 512, koff, A0, A1);   // W_hh1 * h1(t-1)
      mm_half(smem, fa, W1OFF, brow, 0, koff, A0, A1);     // W_ih1 * h0(t)
      g1 = A0 + A1;
      if (wave == 1) {
        float* T1 = (float*)(smem + T1OFF);
#pragma unroll
        for (int j = 0; j < 4; ++j) T1[(rb + j) * 16 + col] = g1[j];
      }
    }
    __syncthreads();  // SYNC2
    if (wave == 0) {
      float hv[4];
      cell_update(smem, g1, bt0_l1, bgb1, bob1, c1r, hv, lane);
      float* BNC = (float*)(smem + BNCOFF);
      if (is_act) {
#pragma unroll
        for (int j = 0; j < 4; ++j) BNC[(rb + j) * 8 + cs] = hv[j];
      }
      asm volatile("s_waitcnt lgkmcnt(0)" ::: "memory");
      float4 v0 = {0, 0, 0, 0}, v1 = {0, 0, 0, 0};
      if (lane < 16) {
        const int row = bg * 16 + lane;
        v0 = *(float4*)(BNC + lane * 8);
        v1 = *(float4*)(BNC + lane * 8 + 4);
        bf16x8 hi = pack8(v0, v1);
        unsigned short* base = h1buf + (size_t)(pp ^ 1) * 2 * BH;
        g_store16(base + (size_t)row * HID + u0, hi);
        bf16x8 lo;  // residual for the BL matmul (w_t row norms ~5.4 amplify h1 error)
        const float* va = (const float*)&v0;
        const float* vb = (const float*)&v1;
#pragma unroll
        for (int q = 0; q < 8; ++q) {
          const float f = (q < 4) ? va[q] : vb[q - 4];
          lo[q] = f2b(f - b2f(hi[q]));
        }
        g_store16(base + BH + (size_t)row * HID + u0, lo);
      }
      if (lane == 0) post_flag(myflag, tb + 3u);
      if (lane < 16) {  // d_out write AFTER the flag (off the critical path)
        const int row = bg * 16 + lane;
        float* od = out + ((size_t)t * BATCH + row) * HID + u0;
        *(float4*)od = v0;
        *(float4*)(od + 4) = v1;
      }
    }

    // ============== PHASE 2: x_{t+1} = h1 @ w_t^T + b_t ==============
    if (t + 1 < T_STEPS) {
      if (wave == 0) {
        poll_flags(cohort, tb + 3u);
        bf16x8 ahi[16], alo[16];
        const unsigned short* hb =
            h1buf + (size_t)(pp ^ 1) * 2 * BH + (size_t)arow * HID + koff;
        g_load_frag(ahi, hb);
        g_load_frag(alo, hb + BH);
        f32x4 A0 = {0, 0, 0, 0}, A1 = {0, 0, 0, 0};
        const unsigned int bb = WSTOFF + (unsigned int)col * 1024u;
        const unsigned int sw = (unsigned int)(col & 7) << 4;
#pragma unroll
        for (int ks = 0; ks < 16; ++ks) {
          bf16x8 b =
              *(const bf16x8*)(smem + ((bb + (unsigned int)((ks * 32 + koff) * 2)) ^ sw));
          A0 = __builtin_amdgcn_mfma_f32_16x16x32_bf16(ahi[ks], b, A0, 0, 0, 0);
          A1 = __builtin_amdgcn_mfma_f32_16x16x32_bf16(alo[ks], b, A1, 0, 0, 0);
        }
        const float ebv = is_act ? ((const float*)(smem + EBOFF))[cs] : 0.f;
        const float xb = bmu_l + bsg_l * ebv;
        f32x4 a2 = A0 + A1;
        float* BNC = (float*)(smem + BNCOFF);
        if (is_act) {
#pragma unroll
          for (int j = 0; j < 4; ++j) BNC[(rb + j) * 8 + cs] = a2[j] + xb;
        }
        asm volatile("s_waitcnt lgkmcnt(0)" ::: "memory");
        if (lane < 16) {
          const int row = bg * 16 + lane;
          float4 v0 = *(float4*)(BNC + lane * 8);
          float4 v1 = *(float4*)(BNC + lane * 8 + 4);
          g_store16(xbuf + (size_t)(pp ^ 1) * BH + (size_t)row * HID + u0, pack8(v0, v1));
        }
        if (lane == 0) post_flag(myflag, tb + 4u);
      }
      __syncthreads();  // trailing: protect wstage/EBOFF rebuild at next loop top
    }
  }
}

extern "C" void kernel_launch(void* const* d_in, const int* in_sizes, int n_in, void* d_out,
                              int out_size, void* d_ws, size_t ws_size, hipStream_t stream) {
  const float* init_h = (const float*)d_in[1];
  const float* init_c = (const float*)d_in[2];
  const float* eps_w = (const float*)d_in[3];
  const float* eps_b = (const float*)d_in[4];
  const float* W_ih0 = (const float*)d_in[5];
  const float* W_hh0 = (const float*)d_in[6];
  const float* b_ih0 = (const float*)d_in[7];
  const float* b_hh0 = (const float*)d_in[8];
  const float* W_ih1 = (const float*)d_in[9];
  const float* W_hh1 = (const float*)d_in[10];
  const float* b_ih1 = (const float*)d_in[11];
  const float* b_hh1 = (const float*)d_in[12];
  const float* w_mu = (const float*)d_in[13];
  const float* w_log_var = (const float*)d_in[14];
  const float* b_mu = (const float*)d_in[15];
  const float* b_log_var = (const float*)d_in[16];
  float* out = (float*)d_out;

  unsigned char* ws = (unsigned char*)d_ws;
  unsigned int* flags = (unsigned int*)ws;                          // 4 cohorts * 1KB
  unsigned short* xbuf = (unsigned short*)(ws + 131072);            // 2 parity * 64*512 bf16
  unsigned short* h0buf = (unsigned short*)(ws + 262144);           // 2 parity
  unsigned short* h1buf = (unsigned short*)(ws + 393216);           // 2 parity * {hi,lo}

  hipMemsetAsync(flags, 0, 4 * 256 * sizeof(unsigned int), stream);
  hipFuncSetAttribute((const void*)dlstm_kernel, hipFuncAttributeMaxDynamicSharedMemorySize,
                      SMEM_BYTES);

  void* args[] = {(void*)&init_h, (void*)&init_c, (void*)&eps_w,  (void*)&eps_b,
                  (void*)&W_ih0,  (void*)&W_hh0,  (void*)&b_ih0,  (void*)&b_hh0,
                  (void*)&W_ih1,  (void*)&W_hh1,  (void*)&b_ih1,  (void*)&b_hh1,
                  (void*)&w_mu,   (void*)&w_log_var, (void*)&b_mu, (void*)&b_log_var,
                  (void*)&out,    (void*)&flags,     (void*)&xbuf, (void*)&h0buf,
                  (void*)&h1buf};
  hipError_t err = hipLaunchCooperativeKernel((void*)dlstm_kernel, dim3(NWG), dim3(NTHR), args,
                                              SMEM_BYTES, stream);
  if (err != hipSuccess) {
    // fallback: plain launch (256 WGs at 1/CU on 256 CUs are co-resident by capacity)
    hipLaunchKernelGGL(dlstm_kernel, dim3(NWG), dim3(NTHR), SMEM_BYTES, stream, init_h, init_c,
                       eps_w, eps_b, W_ih0, W_hh0, b_ih0, b_hh0, W_ih1, W_hh1, b_ih1, b_hh1,
                       w_mu, w_log_var, b_mu, b_log_var, out, flags, xbuf, h0buf, h1buf);
  }
}

// Round 9
// 5184.688 us; speedup vs baseline: 1.4767x; 1.0869x over previous
//
#include <hip/hip_runtime.h>
#include <hip/hip_bf16.h>

#define T_STEPS 256
#define BATCH   64
#define HID     512
#define NWG     256   // 4 batch-groups x 64 unit-groups
#define NTHR    256   // 4 waves

typedef float f32x4 __attribute__((ext_vector_type(4)));
typedef short bf16x8 __attribute__((ext_vector_type(8)));
typedef unsigned long long u64;

// LDS layout (dynamic shared, 1 WG/CU)
#define W0OFF   0u        // [32][1024] bf16, swizzled   (layer0)
#define W1OFF   65536u    // [32][1024] bf16, swizzled   (layer1)
#define WSTOFF  131072u   // [16][512] bf16, swizzled    (w_t rows; rows 8..15 zero)
#define T1OFF   147456u   // [16][16] f32 tile exchange (wave1 -> wave0)
#define BNCOFF  148480u   // [16][8]  f32 bounce (cell lanes -> row writers)
#define EBOFF   148992u   // [8] f32 eps_b slice (wave3 -> wave0)
#define SMEM_BYTES 149024

__device__ __forceinline__ short f2b(float f) {
  __hip_bfloat16 h = __float2bfloat16(f);
  return *reinterpret_cast<short*>(&h);
}
__device__ __forceinline__ float b2f(short s) {
  __hip_bfloat16 h;
  *reinterpret_cast<short*>(&h) = s;
  return __bfloat162float(h);
}
__device__ __forceinline__ float sigf(float x) { return 1.0f / (1.0f + __expf(-x)); }
__device__ __forceinline__ float tanh_f(float x) { return 2.0f / (1.0f + __expf(-2.0f * x)) - 1.0f; }

__device__ __forceinline__ bf16x8 pack8(float4 a, float4 b) {
  bf16x8 r;
  r[0] = f2b(a.x); r[1] = f2b(a.y); r[2] = f2b(a.z); r[3] = f2b(a.w);
  r[4] = f2b(b.x); r[5] = f2b(b.y); r[6] = f2b(b.z); r[7] = f2b(b.w);
  return r;
}

// ---- cross-XCD data movement ----
// STORES must be agent-scope ATOMIC stores: they are vmcnt-acknowledged from
// the COHERENCE POINT (LLC), so post_flag's vmcnt(0) guarantees LLC visibility
// before the flag. Plain sc0sc1 stores ack at XCD egress — the flag can race
// the data through the fabric (rounds 4/8's identical 0.291 failure; round 2
// only passed because its RMW flag added a masking round trip). R6/R7-proven.
__device__ __forceinline__ void g_store16(void* p, bf16x8 v) {
  const u64* s = reinterpret_cast<const u64*>(&v);
  u64* d = reinterpret_cast<u64*>(p);
  __hip_atomic_store(d + 0, s[0], __ATOMIC_RELAXED, __HIP_MEMORY_SCOPE_AGENT);
  __hip_atomic_store(d + 1, s[1], __ATOMIC_RELAXED, __HIP_MEMORY_SCOPE_AGENT);
}
// SAFE burst load: 16 x 16B from LLC with the vmcnt(0) INSIDE the asm block —
// outputs fully valid at block exit, so allocator spills/copies afterwards are
// harmless. Loads overlap each other (16 in flight, one wait). Loads were
// never the race (R2 passed with them); only stores have the egress-ack issue.
__device__ __forceinline__ void llc_load_frag_sync(bf16x8* dst, const unsigned short* p) {
  asm volatile(
      "global_load_dwordx4 %0, %16, off sc0 sc1\n\t"
      "global_load_dwordx4 %1, %16, off offset:64 sc0 sc1\n\t"
      "global_load_dwordx4 %2, %16, off offset:128 sc0 sc1\n\t"
      "global_load_dwordx4 %3, %16, off offset:192 sc0 sc1\n\t"
      "global_load_dwordx4 %4, %16, off offset:256 sc0 sc1\n\t"
      "global_load_dwordx4 %5, %16, off offset:320 sc0 sc1\n\t"
      "global_load_dwordx4 %6, %16, off offset:384 sc0 sc1\n\t"
      "global_load_dwordx4 %7, %16, off offset:448 sc0 sc1\n\t"
      "global_load_dwordx4 %8, %16, off offset:512 sc0 sc1\n\t"
      "global_load_dwordx4 %9, %16, off offset:576 sc0 sc1\n\t"
      "global_load_dwordx4 %10, %16, off offset:640 sc0 sc1\n\t"
      "global_load_dwordx4 %11, %16, off offset:704 sc0 sc1\n\t"
      "global_load_dwordx4 %12, %16, off offset:768 sc0 sc1\n\t"
      "global_load_dwordx4 %13, %16, off offset:832 sc0 sc1\n\t"
      "global_load_dwordx4 %14, %16, off offset:896 sc0 sc1\n\t"
      "global_load_dwordx4 %15, %16, off offset:960 sc0 sc1\n\t"
      "s_waitcnt vmcnt(0)"
      : "=&v"(dst[0]), "=&v"(dst[1]), "=&v"(dst[2]), "=&v"(dst[3]),
        "=&v"(dst[4]), "=&v"(dst[5]), "=&v"(dst[6]), "=&v"(dst[7]),
        "=&v"(dst[8]), "=&v"(dst[9]), "=&v"(dst[10]), "=&v"(dst[11]),
        "=&v"(dst[12]), "=&v"(dst[13]), "=&v"(dst[14]), "=&v"(dst[15])
      : "v"(p)
      : "memory");
}
// Compiler-visible relaxed agent atomic loads: used for STALE-operand prefetch
// that stays in flight across polls/MFMAs — compiler's waitcnt pass tracks the
// defs, so spills/waits are correct by construction (validated rounds 6/7).
__device__ __forceinline__ bf16x8 g_load16(const void* p) {
  const u64* s = reinterpret_cast<const u64*>(p);
  union { u64 q[2]; bf16x8 v; } u;
  u.q[0] = __hip_atomic_load(s + 0, __ATOMIC_RELAXED, __HIP_MEMORY_SCOPE_AGENT);
  u.q[1] = __hip_atomic_load(s + 1, __ATOMIC_RELAXED, __HIP_MEMORY_SCOPE_AGENT);
  return u.v;
}
__device__ __forceinline__ void g_load_frag(bf16x8* dst, const unsigned short* p) {
#pragma unroll
  for (int i = 0; i < 16; ++i) dst[i] = g_load16(p + (size_t)i * 32);
}

// flag post: drain this wave's atomic data stores (LLC-ack'd) then relaxed post.
__device__ __forceinline__ void post_flag(unsigned int* p, unsigned int val) {
  asm volatile("s_waitcnt vmcnt(0)" ::: "memory");
  __hip_atomic_store(p, val, __ATOMIC_RELAXED, __HIP_MEMORY_SCOPE_AGENT);
}
// all 64 lanes; lane i watches cohort[i]; exits when all >= target. Hot spin.
__device__ __forceinline__ void poll_flags(const unsigned int* cohort, unsigned int target) {
  const unsigned int* p = cohort + (threadIdx.x & 63);
  for (;;) {
    unsigned int v = __hip_atomic_load(p, __ATOMIC_RELAXED, __HIP_MEMORY_SCOPE_AGENT);
    if (__all((int)(v >= target))) break;
  }
  __builtin_amdgcn_sched_barrier(0);
}

// stage one layer's gate-row slice (32 rows x 1024 K) fp32 global -> bf16 LDS, XOR-swizzled
__device__ __forceinline__ void stage_weights(char* smem, unsigned int base,
                                              const float* Wih, const float* Whh,
                                              int u0, int tid) {
  for (int p = tid; p < 4096; p += NTHR) {
    const int row = p >> 7;            // 0..31  (0-7 i, 8-15 f, 16-23 g, 24-31 o)
    const int col = (p & 127) * 8;     // 0..1016
    const int gate = row >> 3;
    const int grow = gate * 512 + u0 + (row & 7);
    const float* src = (col < 512) ? (Wih + (size_t)grow * HID + col)
                                   : (Whh + (size_t)grow * HID + (col - 512));
    float4 v0 = *(const float4*)src;
    float4 v1 = *(const float4*)(src + 4);
    unsigned int byte = base + (unsigned int)row * 2048u + (unsigned int)col * 2u;
    byte ^= (unsigned int)(row & 7) << 4;
    *(bf16x8*)(smem + byte) = pack8(v0, v1);
  }
}

// one K=512 product into two interleaved accumulators (two independent chains)
__device__ __forceinline__ void mm_half(const char* smem, const bf16x8* a, unsigned int wOff,
                                        int brow, int colHalf, int koff, f32x4& A0, f32x4& A1) {
  const unsigned int bb = wOff + (unsigned int)brow * 2048u + (unsigned int)colHalf * 2u;
  const unsigned int sw = (unsigned int)(brow & 7) << 4;
#pragma unroll
  for (int ks = 0; ks < 16; ++ks) {
    bf16x8 b = *(const bf16x8*)(smem + ((bb + (unsigned int)((ks * 32 + koff) * 2)) ^ sw));
    if (ks & 1)
      A1 = __builtin_amdgcn_mfma_f32_16x16x32_bf16(a[ks], b, A1, 0, 0, 0);
    else
      A0 = __builtin_amdgcn_mfma_f32_16x16x32_bf16(a[ks], b, A0, 0, 0, 0);
  }
}

// wave0: acc = tile0 [i|f]; T1 in LDS = tile1 [g|o]; produces h (hv) and updates c (cst)
__device__ __forceinline__ void cell_update(char* smem, f32x4 acc, float bt0, float bgb,
                                            float bob, float* cst, float* hv, int lane) {
#pragma unroll
  for (int j = 0; j < 4; ++j) acc[j] += bt0;   // own-column bias (i or f)
  float part[4];
#pragma unroll
  for (int j = 0; j < 4; ++j) part[j] = __shfl_xor(acc[j], 8);
  const float* T1 = (const float*)(smem + T1OFF);
  const int cs = lane & 7;
  const int rb = (lane >> 4) * 4;
#pragma unroll
  for (int j = 0; j < 4; ++j) {
    const float iv = acc[j];                       // valid for lanes col<8
    const float fv = part[j];
    const float gv = T1[(rb + j) * 16 + cs] + bgb;
    const float ov = T1[(rb + j) * 16 + cs + 8] + bob;
    const float cn = sigf(fv) * cst[j] + sigf(iv) * tanh_f(gv);
    cst[j] = cn;
    hv[j] = sigf(ov) * tanh_f(cn);
  }
}

extern "C" __global__ void __launch_bounds__(NTHR, 1)
dlstm_kernel(const float* __restrict__ init_h, const float* __restrict__ init_c,
             const float* __restrict__ eps_w, const float* __restrict__ eps_b,
             const float* __restrict__ W_ih0, const float* __restrict__ W_hh0,
             const float* __restrict__ b_ih0, const float* __restrict__ b_hh0,
             const float* __restrict__ W_ih1, const float* __restrict__ W_hh1,
             const float* __restrict__ b_ih1, const float* __restrict__ b_hh1,
             const float* __restrict__ w_mu, const float* __restrict__ w_log_var,
             const float* __restrict__ b_mu, const float* __restrict__ b_log_var,
             float* __restrict__ out, unsigned int* __restrict__ flags,
             unsigned short* __restrict__ xbuf, unsigned short* __restrict__ h0buf,
             unsigned short* __restrict__ h1buf) {
  extern __shared__ char smem[];
  const int tid = threadIdx.x;
  const int bid = blockIdx.x;
  const int bg = bid & 3;            // batch group (cohort): rows [bg*16, bg*16+16)
  const int u  = bid >> 2;           // unit-slice index 0..63
  const int u0 = u * 8;
  const int wave = tid >> 6;
  const int lane = tid & 63;
  const int col = lane & 15;
  const int cs = lane & 7;
  const int rb = (lane >> 4) * 4;
  const int koff = (lane >> 4) * 8;
  const bool is_act = col < 8;
  const size_t BH = (size_t)BATCH * HID;
  unsigned int* cohort = flags + bg * 256;   // 1KB-strided cohorts (64 WGs each)
  unsigned int* myflag = cohort + u;
  const int arow = bg * 16 + col;
  const int brow = wave * 16 + col;

  // ---------------- one-time init ----------------
  stage_weights(smem, W0OFF, W_ih0, W_hh0, u0, tid);
  stage_weights(smem, W1OFF, W_ih1, W_hh1, u0, tid);
  {  // zero wstage pad rows 8..15 (MFMA N-tile is 16 wide, only 8 real rows)
    bf16x8 z = {0, 0, 0, 0, 0, 0, 0, 0};
    for (int p = tid; p < 512; p += NTHR) {
      const int row = 8 + (p >> 6);
      const int c8 = (p & 63) * 8;
      unsigned int byte = WSTOFF + (unsigned int)row * 1024u + (unsigned int)c8 * 2u;
      byte ^= (unsigned int)(row & 7) << 4;
      *(bf16x8*)(smem + byte) = z;
    }
  }
  // wave0 per-lane constants + states
  float bt0_l0 = 0, bt0_l1 = 0, bgb0 = 0, bob0 = 0, bgb1 = 0, bob1 = 0, bmu_l = 0, bsg_l = 0;
  float c0r[4] = {0, 0, 0, 0}, c1r[4] = {0, 0, 0, 0};
  if (wave == 0) {
    const int ofs = (col < 8) ? 0 : 512;
    const int un = u0 + cs;
    bt0_l0 = b_ih0[ofs + un] + b_hh0[ofs + un];
    bt0_l1 = b_ih1[ofs + un] + b_hh1[ofs + un];
    bgb0 = b_ih0[1024 + un] + b_hh0[1024 + un];
    bob0 = b_ih0[1536 + un] + b_hh0[1536 + un];
    bgb1 = b_ih1[1024 + un] + b_hh1[1024 + un];
    bob1 = b_ih1[1536 + un] + b_hh1[1536 + un];
    bmu_l = b_mu[un];
    bsg_l = __expf(0.5f * b_log_var[un]);
    if (is_act) {
#pragma unroll
      for (int j = 0; j < 4; ++j) {
        c0r[j] = init_c[(size_t)(0 * BATCH + bg * 16 + rb + j) * HID + un];
        c1r[j] = init_c[(size_t)(1 * BATCH + bg * 16 + rb + j) * HID + un];
      }
    }
    if (lane < 16) {  // write this WG's tile of the parity-0 state buffers
      const int row = bg * 16 + lane;
      const float* s0 = init_h + (size_t)row * HID + u0;
      const float* s1 = init_h + (size_t)(BATCH + row) * HID + u0;
      g_store16(h0buf + (size_t)row * HID + u0,
                pack8(*(const float4*)s0, *(const float4*)(s0 + 4)));
      g_store16(h1buf + (size_t)row * HID + u0,
                pack8(*(const float4*)s1, *(const float4*)(s1 + 4)));
      bf16x8 z = {0, 0, 0, 0, 0, 0, 0, 0};
      g_store16(xbuf + (size_t)row * HID + u0, z);  // x_0 = 0
    }
    if (lane == 0) post_flag(myflag, 1u);   // vmcnt-drain + relaxed post
  }
  __syncthreads();  // SYNC0: LDS weight staging complete

  // ---------------- time loop ----------------
#pragma unroll 1
  for (int t = 0; t < T_STEPS; ++t) {
    const int pp = t & 1;
    const unsigned int tb = 3u * (unsigned int)t;

    // stale-operand prefetch: h0(t-1) flag (3(t-1)+2) already confirmed by both
    // worker waves' last polls for t>0 — issue now, in flight during the poll.
    bf16x8 sa[16];
    if (wave < 2 && t > 0) {
      g_load_frag(sa, h0buf + (size_t)pp * BH + (size_t)arow * HID + koff);
      __builtin_amdgcn_sched_barrier(0);
    }

    // waves 2/3: build w_t into LDS (plain cached loads — read-only inputs,
    // off the critical path), stage eps_b[t] for wave0
    if (wave >= 2) {
      const int q = tid - 128;       // 0..127
      const int erow = q >> 4;       // 0..7
      const int ecb = (q & 15) * 32; // 0..480
      const float* pm = w_mu + (size_t)(u0 + erow) * HID + ecb;
      const float* pv = w_log_var + (size_t)(u0 + erow) * HID + ecb;
      const float* pe = eps_w + (size_t)t * HID * HID + (size_t)(u0 + erow) * HID + ecb;
      const unsigned int sw = (unsigned int)erow << 4;
      const unsigned int b0 = WSTOFF + (unsigned int)erow * 1024u + (unsigned int)ecb * 2u;
#pragma unroll
      for (int c = 0; c < 4; ++c) {
        bf16x8 v;
#pragma unroll
        for (int qq = 0; qq < 8; ++qq) {
          const int idx = c * 8 + qq;
          v[qq] = f2b(fmaf(__expf(0.5f * pv[idx]), pe[idx], pm[idx]));
        }
        *(bf16x8*)(smem + ((b0 + (unsigned int)c * 16u) ^ sw)) = v;
      }
      if (wave == 3 && lane < 8)
        ((float*)(smem + EBOFF))[lane] = eps_b[(size_t)t * HID + u0 + lane];
    }

    // ============== PHASE 0: gates0 -> h0 ==============
    f32x4 g0 = {0.f, 0.f, 0.f, 0.f};
    bf16x8 sth1[16];   // stale h1(t-1) prefetch, consumed in phase 1
    if (wave < 2) {
      poll_flags(cohort, tb + 1u);
      if (t == 0) {  // init flags only now confirmed
        g_load_frag(sa, h0buf + (size_t)pp * BH + (size_t)arow * HID + koff);
      }
      bf16x8 fa[16];
      llc_load_frag_sync(fa, xbuf + (size_t)pp * BH + (size_t)arow * HID + koff);
      // h1(t-1) flag (=3t) is implied by tb+1; issue prefetch to fly under MFMAs
      g_load_frag(sth1, h1buf + (size_t)pp * 2 * BH + (size_t)arow * HID + koff);
      __builtin_amdgcn_sched_barrier(0);
      f32x4 A0 = {0, 0, 0, 0}, A1 = {0, 0, 0, 0};
      mm_half(smem, sa, W0OFF, brow, 512, koff, A0, A1);   // W_hh0 * h0(t-1)
      mm_half(smem, fa, W0OFF, brow, 0, koff, A0, A1);     // W_ih0 * x(t)
      g0 = A0 + A1;
      if (wave == 1) {
        float* T1 = (float*)(smem + T1OFF);
#pragma unroll
        for (int j = 0; j < 4; ++j) T1[(rb + j) * 16 + col] = g0[j];
      }
    }
    __syncthreads();  // SYNC1
    if (wave == 0) {
      float hv[4];
      cell_update(smem, g0, bt0_l0, bgb0, bob0, c0r, hv, lane);
      float* BNC = (float*)(smem + BNCOFF);
      if (is_act) {
#pragma unroll
        for (int j = 0; j < 4; ++j) BNC[(rb + j) * 8 + cs] = hv[j];
      }
      asm volatile("s_waitcnt lgkmcnt(0)" ::: "memory");
      if (lane < 16) {
        const int row = bg * 16 + lane;
        float4 v0 = *(float4*)(BNC + lane * 8);
        float4 v1 = *(float4*)(BNC + lane * 8 + 4);
        g_store16(h0buf + (size_t)(pp ^ 1) * BH + (size_t)row * HID + u0, pack8(v0, v1));
      }
      if (lane == 0) post_flag(myflag, tb + 2u);
    }

    // ============== PHASE 1: gates1 -> h1 (+ d_out) ==============
    f32x4 g1 = {0.f, 0.f, 0.f, 0.f};
    if (wave < 2) {
      poll_flags(cohort, tb + 2u);
      bf16x8 fa[16];
      llc_load_frag_sync(fa, h0buf + (size_t)(pp ^ 1) * BH + (size_t)arow * HID + koff);
      f32x4 A0 = {0, 0, 0, 0}, A1 = {0, 0, 0, 0};
      mm_half(smem, sth1, W1OFF, brow, 512, koff, A0, A1); // W_hh1 * h1(t-1) (prefetched)
      mm_half(smem, fa, W1OFF, brow, 0, koff, A0, A1);     // W_ih1 * h0(t)
      g1 = A0 + A1;
      if (wave == 1) {
        float* T1 = (float*)(smem + T1OFF);
#pragma unroll
        for (int j = 0; j < 4; ++j) T1[(rb + j) * 16 + col] = g1[j];
      }
    }
    __syncthreads();  // SYNC2
    if (wave == 0) {
      float hv[4];
      cell_update(smem, g1, bt0_l1, bgb1, bob1, c1r, hv, lane);
      float* BNC = (float*)(smem + BNCOFF);
      if (is_act) {
#pragma unroll
        for (int j = 0; j < 4; ++j) BNC[(rb + j) * 8 + cs] = hv[j];
      }
      asm volatile("s_waitcnt lgkmcnt(0)" ::: "memory");
      float4 v0 = {0, 0, 0, 0}, v1 = {0, 0, 0, 0};
      if (lane < 16) {
        const int row = bg * 16 + lane;
        v0 = *(float4*)(BNC + lane * 8);
        v1 = *(float4*)(BNC + lane * 8 + 4);
        bf16x8 hi = pack8(v0, v1);
        unsigned short* base = h1buf + (size_t)(pp ^ 1) * 2 * BH;
        g_store16(base + (size_t)row * HID + u0, hi);
        bf16x8 lo;  // residual for the BL matmul (w_t row norms ~5.4 amplify h1 error)
        const float* va = (const float*)&v0;
        const float* vb = (const float*)&v1;
#pragma unroll
        for (int q = 0; q < 8; ++q) {
          const float f = (q < 4) ? va[q] : vb[q - 4];
          lo[q] = f2b(f - b2f(hi[q]));
        }
        g_store16(base + BH + (size_t)row * HID + u0, lo);
      }
      if (lane == 0) post_flag(myflag, tb + 3u);
      if (lane < 16) {  // d_out write AFTER the flag (off the critical path)
        const int row = bg * 16 + lane;
        float* od = out + ((size_t)t * BATCH + row) * HID + u0;
        *(float4*)od = v0;
        *(float4*)(od + 4) = v1;
      }
    }

    // ============== PHASE 2: x_{t+1} = h1 @ w_t^T + b_t ==============
    if (t + 1 < T_STEPS) {
      if (wave == 0) {
        poll_flags(cohort, tb + 3u);
        bf16x8 ahi[16], alo[16];
        const unsigned short* hb =
            h1buf + (size_t)(pp ^ 1) * 2 * BH + (size_t)arow * HID + koff;
        llc_load_frag_sync(ahi, hb);
        llc_load_frag_sync(alo, hb + BH);
        f32x4 A0 = {0, 0, 0, 0}, A1 = {0, 0, 0, 0};
        const unsigned int bb = WSTOFF + (unsigned int)col * 1024u;
        const unsigned int sw = (unsigned int)(col & 7) << 4;
#pragma unroll
        for (int ks = 0; ks < 16; ++ks) {
          bf16x8 b =
              *(const bf16x8*)(smem + ((bb + (unsigned int)((ks * 32 + koff) * 2)) ^ sw));
          A0 = __builtin_amdgcn_mfma_f32_16x16x32_bf16(ahi[ks], b, A0, 0, 0, 0);
          A1 = __builtin_amdgcn_mfma_f32_16x16x32_bf16(alo[ks], b, A1, 0, 0, 0);
        }
        const float ebv = is_act ? ((const float*)(smem + EBOFF))[cs] : 0.f;
        const float xb = bmu_l + bsg_l * ebv;
        f32x4 a2 = A0 + A1;
        float* BNC = (float*)(smem + BNCOFF);
        if (is_act) {
#pragma unroll
          for (int j = 0; j < 4; ++j) BNC[(rb + j) * 8 + cs] = a2[j] + xb;
        }
        asm volatile("s_waitcnt lgkmcnt(0)" ::: "memory");
        if (lane < 16) {
          const int row = bg * 16 + lane;
          float4 v0 = *(float4*)(BNC + lane * 8);
          float4 v1 = *(float4*)(BNC + lane * 8 + 4);
          g_store16(xbuf + (size_t)(pp ^ 1) * BH + (size_t)row * HID + u0, pack8(v0, v1));
        }
        if (lane == 0) post_flag(myflag, tb + 4u);
      }
      __syncthreads();  // trailing: protect wstage/EBOFF rebuild at next loop top
    }
  }
}

extern "C" void kernel_launch(void* const* d_in, const int* in_sizes, int n_in, void* d_out,
                              int out_size, void* d_ws, size_t ws_size, hipStream_t stream) {
  const float* init_h = (const float*)d_in[1];
  const float* init_c = (const float*)d_in[2];
  const float* eps_w = (const float*)d_in[3];
  const float* eps_b = (const float*)d_in[4];
  const float* W_ih0 = (const float*)d_in[5];
  const float* W_hh0 = (const float*)d_in[6];
  const float* b_ih0 = (const float*)d_in[7];
  const float* b_hh0 = (const float*)d_in[8];
  const float* W_ih1 = (const float*)d_in[9];
  const float* W_hh1 = (const float*)d_in[10];
  const float* b_ih1 = (const float*)d_in[11];
  const float* b_hh1 = (const float*)d_in[12];
  const float* w_mu = (const float*)d_in[13];
  const float* w_log_var = (const float*)d_in[14];
  const float* b_mu = (const float*)d_in[15];
  const float* b_log_var = (const float*)d_in[16];
  float* out = (float*)d_out;

  unsigned char* ws = (unsigned char*)d_ws;
  unsigned int* flags = (unsigned int*)ws;                          // 4 cohorts * 1KB
  unsigned short* xbuf = (unsigned short*)(ws + 131072);            // 2 parity * 64*512 bf16
  unsigned short* h0buf = (unsigned short*)(ws + 262144);           // 2 parity
  unsigned short* h1buf = (unsigned short*)(ws + 393216);           // 2 parity * {hi,lo}

  hipMemsetAsync(flags, 0, 4 * 256 * sizeof(unsigned int), stream);
  hipFuncSetAttribute((const void*)dlstm_kernel, hipFuncAttributeMaxDynamicSharedMemorySize,
                      SMEM_BYTES);

  void* args[] = {(void*)&init_h, (void*)&init_c, (void*)&eps_w,  (void*)&eps_b,
                  (void*)&W_ih0,  (void*)&W_hh0,  (void*)&b_ih0,  (void*)&b_hh0,
                  (void*)&W_ih1,  (void*)&W_hh1,  (void*)&b_ih1,  (void*)&b_hh1,
                  (void*)&w_mu,   (void*)&w_log_var, (void*)&b_mu, (void*)&b_log_var,
                  (void*)&out,    (void*)&flags,     (void*)&xbuf, (void*)&h0buf,
                  (void*)&h1buf};
  hipError_t err = hipLaunchCooperativeKernel((void*)dlstm_kernel, dim3(NWG), dim3(NTHR), args,
                                              SMEM_BYTES, stream);
  if (err != hipSuccess) {
    // fallback: plain launch (256 WGs at 1/CU on 256 CUs are co-resident by capacity)
    hipLaunchKernelGGL(dlstm_kernel, dim3(NWG), dim3(NTHR), SMEM_BYTES, stream, init_h, init_c,
                       eps_w, eps_b, W_ih0, W_hh0, b_ih0, b_hh0, W_ih1, W_hh1, b_ih1, b_hh1,
                       w_mu, w_log_var, b_mu, b_log_var, out, flags, xbuf, h0buf, h1buf);
  }
}

// Round 10
// 5106.691 us; speedup vs baseline: 1.4992x; 1.0153x over previous
//
#include <hip/hip_runtime.h>
#include <hip/hip_bf16.h>

#define T_STEPS 256
#define BATCH   64
#define HID     512
#define NWG     256   // 4 batch-groups x 64 unit-groups
#define NTHR    256   // 4 waves

typedef float f32x4 __attribute__((ext_vector_type(4)));
typedef short bf16x8 __attribute__((ext_vector_type(8)));
typedef short bf16x4 __attribute__((ext_vector_type(4)));
typedef unsigned long long u64;

// LDS layout (dynamic shared, 1 WG/CU)
#define W0OFF   0u        // [32][1024] bf16, swizzled   (layer0)
#define W1OFF   65536u    // [32][1024] bf16, swizzled   (layer1)
#define WSTOFF  131072u   // TWO buffers [8][512] bf16 swizzled (+ pp*8192): w_t rows 0..7
#define ZPADOFF 147456u   // [8][512] bf16 zeros (shared MFMA B rows 8..15)
#define T1OFF   155648u   // [16][16] f32 tile exchange (wave1 -> wave0)
#define BNCOFF  156672u   // [16][8]  f32 bounce (cell lanes -> row writers)
#define EBOFF   157184u   // TWO buffers [8] f32 eps_b slice (+ pp*32)
#define SMEM_BYTES 157248

__device__ __forceinline__ short f2b(float f) {
  __hip_bfloat16 h = __float2bfloat16(f);
  return *reinterpret_cast<short*>(&h);
}
__device__ __forceinline__ float b2f(short s) {
  __hip_bfloat16 h;
  *reinterpret_cast<short*>(&h) = s;
  return __bfloat162float(h);
}
__device__ __forceinline__ float sigf(float x) { return 1.0f / (1.0f + __expf(-x)); }
__device__ __forceinline__ float tanh_f(float x) { return 2.0f / (1.0f + __expf(-2.0f * x)) - 1.0f; }

__device__ __forceinline__ bf16x8 pack8(float4 a, float4 b) {
  bf16x8 r;
  r[0] = f2b(a.x); r[1] = f2b(a.y); r[2] = f2b(a.z); r[3] = f2b(a.w);
  r[4] = f2b(b.x); r[5] = f2b(b.y); r[6] = f2b(b.z); r[7] = f2b(b.w);
  return r;
}

// ---- cross-XCD data movement (R9-proven protocol) ----
// STORES: agent-scope ATOMIC stores — vmcnt-acknowledged from the coherence
// point (LLC), so post_flag's vmcnt(0) guarantees LLC visibility before the
// flag. Plain sc0sc1 stores ack at XCD egress and race the flag (R4/R8).
__device__ __forceinline__ void g_store16(void* p, bf16x8 v) {
  const u64* s = reinterpret_cast<const u64*>(&v);
  u64* d = reinterpret_cast<u64*>(p);
  __hip_atomic_store(d + 0, s[0], __ATOMIC_RELAXED, __HIP_MEMORY_SCOPE_AGENT);
  __hip_atomic_store(d + 1, s[1], __ATOMIC_RELAXED, __HIP_MEMORY_SCOPE_AGENT);
}
// SAFE burst load: 16 x 16B from LLC with the vmcnt(0) INSIDE the asm block —
// outputs fully valid at block exit (no allocator spill hazard).
__device__ __forceinline__ void llc_load_frag_sync(bf16x8* dst, const unsigned short* p) {
  asm volatile(
      "global_load_dwordx4 %0, %16, off sc0 sc1\n\t"
      "global_load_dwordx4 %1, %16, off offset:64 sc0 sc1\n\t"
      "global_load_dwordx4 %2, %16, off offset:128 sc0 sc1\n\t"
      "global_load_dwordx4 %3, %16, off offset:192 sc0 sc1\n\t"
      "global_load_dwordx4 %4, %16, off offset:256 sc0 sc1\n\t"
      "global_load_dwordx4 %5, %16, off offset:320 sc0 sc1\n\t"
      "global_load_dwordx4 %6, %16, off offset:384 sc0 sc1\n\t"
      "global_load_dwordx4 %7, %16, off offset:448 sc0 sc1\n\t"
      "global_load_dwordx4 %8, %16, off offset:512 sc0 sc1\n\t"
      "global_load_dwordx4 %9, %16, off offset:576 sc0 sc1\n\t"
      "global_load_dwordx4 %10, %16, off offset:640 sc0 sc1\n\t"
      "global_load_dwordx4 %11, %16, off offset:704 sc0 sc1\n\t"
      "global_load_dwordx4 %12, %16, off offset:768 sc0 sc1\n\t"
      "global_load_dwordx4 %13, %16, off offset:832 sc0 sc1\n\t"
      "global_load_dwordx4 %14, %16, off offset:896 sc0 sc1\n\t"
      "global_load_dwordx4 %15, %16, off offset:960 sc0 sc1\n\t"
      "s_waitcnt vmcnt(0)"
      : "=&v"(dst[0]), "=&v"(dst[1]), "=&v"(dst[2]), "=&v"(dst[3]),
        "=&v"(dst[4]), "=&v"(dst[5]), "=&v"(dst[6]), "=&v"(dst[7]),
        "=&v"(dst[8]), "=&v"(dst[9]), "=&v"(dst[10]), "=&v"(dst[11]),
        "=&v"(dst[12]), "=&v"(dst[13]), "=&v"(dst[14]), "=&v"(dst[15])
      : "v"(p)
      : "memory");
}
// Compiler-visible relaxed agent atomic loads: stale-operand prefetch left in
// flight across polls/MFMAs (compiler's waitcnt pass tracks the defs).
__device__ __forceinline__ bf16x8 g_load16(const void* p) {
  const u64* s = reinterpret_cast<const u64*>(p);
  union { u64 q[2]; bf16x8 v; } u;
  u.q[0] = __hip_atomic_load(s + 0, __ATOMIC_RELAXED, __HIP_MEMORY_SCOPE_AGENT);
  u.q[1] = __hip_atomic_load(s + 1, __ATOMIC_RELAXED, __HIP_MEMORY_SCOPE_AGENT);
  return u.v;
}
__device__ __forceinline__ void g_load_frag(bf16x8* dst, const unsigned short* p) {
#pragma unroll
  for (int i = 0; i < 16; ++i) dst[i] = g_load16(p + (size_t)i * 32);
}

// flag post: drain this wave's atomic data stores (LLC-ack'd) then relaxed post.
__device__ __forceinline__ void post_flag(unsigned int* p, unsigned int val) {
  asm volatile("s_waitcnt vmcnt(0)" ::: "memory");
  __hip_atomic_store(p, val, __ATOMIC_RELAXED, __HIP_MEMORY_SCOPE_AGENT);
}
// all 64 lanes; lane i watches cohort[i]; exits when all >= target. Hot spin.
__device__ __forceinline__ void poll_flags(const unsigned int* cohort, unsigned int target) {
  const unsigned int* p = cohort + (threadIdx.x & 63);
  for (;;) {
    unsigned int v = __hip_atomic_load(p, __ATOMIC_RELAXED, __HIP_MEMORY_SCOPE_AGENT);
    if (__all((int)(v >= target))) break;
  }
  __builtin_amdgcn_sched_barrier(0);
}

// stage one layer's gate-row slice (32 rows x 1024 K) fp32 global -> bf16 LDS, XOR-swizzled
__device__ __forceinline__ void stage_weights(char* smem, unsigned int base,
                                              const float* Wih, const float* Whh,
                                              int u0, int tid) {
  for (int p = tid; p < 4096; p += NTHR) {
    const int row = p >> 7;            // 0..31  (0-7 i, 8-15 f, 16-23 g, 24-31 o)
    const int col = (p & 127) * 8;     // 0..1016
    const int gate = row >> 3;
    const int grow = gate * 512 + u0 + (row & 7);
    const float* src = (col < 512) ? (Wih + (size_t)grow * HID + col)
                                   : (Whh + (size_t)grow * HID + (col - 512));
    float4 v0 = *(const float4*)src;
    float4 v1 = *(const float4*)(src + 4);
    unsigned int byte = base + (unsigned int)row * 2048u + (unsigned int)col * 2u;
    byte ^= (unsigned int)(row & 7) << 4;
    *(bf16x8*)(smem + byte) = pack8(v0, v1);
  }
}

// one K=512 product into two interleaved accumulators (two independent chains)
__device__ __forceinline__ void mm_half(const char* smem, const bf16x8* a, unsigned int wOff,
                                        int brow, int colHalf, int koff, f32x4& A0, f32x4& A1) {
  const unsigned int bb = wOff + (unsigned int)brow * 2048u + (unsigned int)colHalf * 2u;
  const unsigned int sw = (unsigned int)(brow & 7) << 4;
#pragma unroll
  for (int ks = 0; ks < 16; ++ks) {
    bf16x8 b = *(const bf16x8*)(smem + ((bb + (unsigned int)((ks * 32 + koff) * 2)) ^ sw));
    if (ks & 1)
      A1 = __builtin_amdgcn_mfma_f32_16x16x32_bf16(a[ks], b, A1, 0, 0, 0);
    else
      A0 = __builtin_amdgcn_mfma_f32_16x16x32_bf16(a[ks], b, A0, 0, 0, 0);
  }
}

// wave0: acc = tile0 [i|f]; T1 in LDS = tile1 [g|o]; produces h (hv) and updates c (cst)
__device__ __forceinline__ void cell_update(char* smem, f32x4 acc, float bt0, float bgb,
                                            float bob, float* cst, float* hv, int lane) {
#pragma unroll
  for (int j = 0; j < 4; ++j) acc[j] += bt0;   // own-column bias (i or f)
  float part[4];
#pragma unroll
  for (int j = 0; j < 4; ++j) part[j] = __shfl_xor(acc[j], 8);
  const float* T1 = (const float*)(smem + T1OFF);
  const int cs = lane & 7;
  const int rb = (lane >> 4) * 4;
#pragma unroll
  for (int j = 0; j < 4; ++j) {
    const float iv = acc[j];                       // valid for lanes col<8
    const float fv = part[j];
    const float gv = T1[(rb + j) * 16 + cs] + bgb;
    const float ov = T1[(rb + j) * 16 + cs + 8] + bob;
    const float cn = sigf(fv) * cst[j] + sigf(iv) * tanh_f(gv);
    cst[j] = cn;
    hv[j] = sigf(ov) * tanh_f(cn);
  }
}

extern "C" __global__ void __launch_bounds__(NTHR, 1)
dlstm_kernel(const float* __restrict__ init_h, const float* __restrict__ init_c,
             const float* __restrict__ eps_w, const float* __restrict__ eps_b,
             const float* __restrict__ W_ih0, const float* __restrict__ W_hh0,
             const float* __restrict__ b_ih0, const float* __restrict__ b_hh0,
             const float* __restrict__ W_ih1, const float* __restrict__ W_hh1,
             const float* __restrict__ b_ih1, const float* __restrict__ b_hh1,
             const float* __restrict__ w_mu, const float* __restrict__ w_log_var,
             const float* __restrict__ b_mu, const float* __restrict__ b_log_var,
             float* __restrict__ out, unsigned int* __restrict__ flags,
             unsigned short* __restrict__ xbuf, unsigned short* __restrict__ h0buf,
             unsigned short* __restrict__ h1buf) {
  extern __shared__ char smem[];
  const int tid = threadIdx.x;
  const int bid = blockIdx.x;
  const int bg = bid & 3;            // batch group (cohort): rows [bg*16, bg*16+16)
  const int u  = bid >> 2;           // unit-slice index 0..63
  const int u0 = u * 8;
  const int wave = tid >> 6;
  const int lane = tid & 63;
  const int col = lane & 15;
  const int cs = lane & 7;
  const int rb = (lane >> 4) * 4;
  const int koff = (lane >> 4) * 8;
  const bool is_act = col < 8;
  const size_t BH = (size_t)BATCH * HID;
  unsigned int* cohort = flags + bg * 256;   // 1KB-strided cohorts (64 WGs each)
  unsigned int* myflag = cohort + u;
  const int arow = bg * 16 + col;
  const int brow = wave * 16 + col;

  // ---------------- one-time init ----------------
  stage_weights(smem, W0OFF, W_ih0, W_hh0, u0, tid);
  stage_weights(smem, W1OFF, W_ih1, W_hh1, u0, tid);
  {  // zero the shared MFMA-B pad (rows 8..15 of the w_t tile read zeros here)
    bf16x8 z = {0, 0, 0, 0, 0, 0, 0, 0};
    for (int p = tid; p < 512; p += NTHR)
      *(bf16x8*)(smem + ZPADOFF + (unsigned int)p * 16u) = z;
  }
  // waves 2/3: cache w_mu / sigma rows in registers (step-invariant), COALESCED:
  // thread q owns (row k, cols 4q..4q+3) for k=0..7 — lane-contiguous float4s.
  const int q4 = (tid - 128) * 4;   // valid for wave>=2
  float4 mu4[8], sg4[8];
  if (wave >= 2) {
#pragma unroll
    for (int k = 0; k < 8; ++k) {
      mu4[k] = *(const float4*)(w_mu + (size_t)(u0 + k) * HID + q4);
      float4 lv = *(const float4*)(w_log_var + (size_t)(u0 + k) * HID + q4);
      sg4[k].x = __expf(0.5f * lv.x); sg4[k].y = __expf(0.5f * lv.y);
      sg4[k].z = __expf(0.5f * lv.z); sg4[k].w = __expf(0.5f * lv.w);
    }
  }
  // wave0 per-lane constants + states
  float bt0_l0 = 0, bt0_l1 = 0, bgb0 = 0, bob0 = 0, bgb1 = 0, bob1 = 0, bmu_l = 0, bsg_l = 0;
  float c0r[4] = {0, 0, 0, 0}, c1r[4] = {0, 0, 0, 0};
  if (wave == 0) {
    const int ofs = (col < 8) ? 0 : 512;
    const int un = u0 + cs;
    bt0_l0 = b_ih0[ofs + un] + b_hh0[ofs + un];
    bt0_l1 = b_ih1[ofs + un] + b_hh1[ofs + un];
    bgb0 = b_ih0[1024 + un] + b_hh0[1024 + un];
    bob0 = b_ih0[1536 + un] + b_hh0[1536 + un];
    bgb1 = b_ih1[1024 + un] + b_hh1[1024 + un];
    bob1 = b_ih1[1536 + un] + b_hh1[1536 + un];
    bmu_l = b_mu[un];
    bsg_l = __expf(0.5f * b_log_var[un]);
    if (is_act) {
#pragma unroll
      for (int j = 0; j < 4; ++j) {
        c0r[j] = init_c[(size_t)(0 * BATCH + bg * 16 + rb + j) * HID + un];
        c1r[j] = init_c[(size_t)(1 * BATCH + bg * 16 + rb + j) * HID + un];
      }
    }
    if (lane < 16) {  // write this WG's tile of the parity-0 state buffers
      const int row = bg * 16 + lane;
      const float* s0 = init_h + (size_t)row * HID + u0;
      const float* s1 = init_h + (size_t)(BATCH + row) * HID + u0;
      g_store16(h0buf + (size_t)row * HID + u0,
                pack8(*(const float4*)s0, *(const float4*)(s0 + 4)));
      g_store16(h1buf + (size_t)row * HID + u0,
                pack8(*(const float4*)s1, *(const float4*)(s1 + 4)));
      bf16x8 z = {0, 0, 0, 0, 0, 0, 0, 0};
      g_store16(xbuf + (size_t)row * HID + u0, z);  // x_0 = 0
    }
    if (lane == 0) post_flag(myflag, 1u);   // vmcnt-drain + relaxed post
  }
  __syncthreads();  // SYNC0: LDS weight staging complete

  // ---------------- time loop ----------------
#pragma unroll 1
  for (int t = 0; t < T_STEPS; ++t) {
    const int pp = t & 1;
    const unsigned int tb = 3u * (unsigned int)t;

    // stale-operand prefetch: h0(t-1) flag (3(t-1)+2) already confirmed by both
    // worker waves' last polls for t>0 — issue now, in flight during the poll.
    bf16x8 sa[16];
    if (wave < 2 && t > 0) {
      g_load_frag(sa, h0buf + (size_t)pp * BH + (size_t)arow * HID + koff);
      __builtin_amdgcn_sched_barrier(0);
    }

    // waves 2/3: build w_t into LDS buffer [pp] (coalesced float4 eps loads,
    // registered mu/sigma), stage eps_b[t] into EB[pp]. Double-buffered, so no
    // trailing barrier needed: phase-2(t) reads buf pp while wstage(t+1)
    // writes buf pp^1; same-parity reuse is ordered by the phase-0 poll chain.
    if (wave >= 2) {
      const float* pe = eps_w + (size_t)t * HID * HID + (size_t)u0 * HID + q4;
      const unsigned int wb = WSTOFF + (unsigned int)pp * 8192u + (unsigned int)q4 * 2u;
#pragma unroll
      for (int k = 0; k < 8; ++k) {
        float4 e = *(const float4*)(pe + (size_t)k * HID);
        bf16x4 v;
        v[0] = f2b(fmaf(sg4[k].x, e.x, mu4[k].x));
        v[1] = f2b(fmaf(sg4[k].y, e.y, mu4[k].y));
        v[2] = f2b(fmaf(sg4[k].z, e.z, mu4[k].z));
        v[3] = f2b(fmaf(sg4[k].w, e.w, mu4[k].w));
        unsigned int byte = (wb + (unsigned int)k * 1024u) ^ ((unsigned int)k << 4);
        *(bf16x4*)(smem + byte) = v;
      }
      if (wave == 3 && lane < 8)
        ((float*)(smem + EBOFF + pp * 32))[lane] = eps_b[(size_t)t * HID + u0 + lane];
    }

    // ============== PHASE 0: gates0 -> h0 ==============
    f32x4 g0 = {0.f, 0.f, 0.f, 0.f};
    bf16x8 sth1[16];   // stale h1(t-1) prefetch, consumed in phase 1
    if (wave < 2) {
      poll_flags(cohort, tb + 1u);
      if (t == 0) {  // init flags only now confirmed
        g_load_frag(sa, h0buf + (size_t)pp * BH + (size_t)arow * HID + koff);
      }
      bf16x8 fa[16];
      llc_load_frag_sync(fa, xbuf + (size_t)pp * BH + (size_t)arow * HID + koff);
      // h1(t-1) flag (=3t) is implied by tb+1; issue prefetch to fly under MFMAs
      g_load_frag(sth1, h1buf + (size_t)pp * 2 * BH + (size_t)arow * HID + koff);
      __builtin_amdgcn_sched_barrier(0);
      f32x4 A0 = {0, 0, 0, 0}, A1 = {0, 0, 0, 0};
      mm_half(smem, sa, W0OFF, brow, 512, koff, A0, A1);   // W_hh0 * h0(t-1)
      mm_half(smem, fa, W0OFF, brow, 0, koff, A0, A1);     // W_ih0 * x(t)
      g0 = A0 + A1;
      if (wave == 1) {
        float* T1 = (float*)(smem + T1OFF);
#pragma unroll
        for (int j = 0; j < 4; ++j) T1[(rb + j) * 16 + col] = g0[j];
      }
    }
    __syncthreads();  // SYNC1
    if (wave == 0) {
      float hv[4];
      cell_update(smem, g0, bt0_l0, bgb0, bob0, c0r, hv, lane);
      float* BNC = (float*)(smem + BNCOFF);
      if (is_act) {
#pragma unroll
        for (int j = 0; j < 4; ++j) BNC[(rb + j) * 8 + cs] = hv[j];
      }
      asm volatile("s_waitcnt lgkmcnt(0)" ::: "memory");
      if (lane < 16) {
        const int row = bg * 16 + lane;
        float4 v0 = *(float4*)(BNC + lane * 8);
        float4 v1 = *(float4*)(BNC + lane * 8 + 4);
        g_store16(h0buf + (size_t)(pp ^ 1) * BH + (size_t)row * HID + u0, pack8(v0, v1));
      }
      if (lane == 0) post_flag(myflag, tb + 2u);
    }

    // ============== PHASE 1: gates1 -> h1 (+ d_out) ==============
    f32x4 g1 = {0.f, 0.f, 0.f, 0.f};
    if (wave < 2) {
      poll_flags(cohort, tb + 2u);
      bf16x8 fa[16];
      llc_load_frag_sync(fa, h0buf + (size_t)(pp ^ 1) * BH + (size_t)arow * HID + koff);
      f32x4 A0 = {0, 0, 0, 0}, A1 = {0, 0, 0, 0};
      mm_half(smem, sth1, W1OFF, brow, 512, koff, A0, A1); // W_hh1 * h1(t-1) (prefetched)
      mm_half(smem, fa, W1OFF, brow, 0, koff, A0, A1);     // W_ih1 * h0(t)
      g1 = A0 + A1;
      if (wave == 1) {
        float* T1 = (float*)(smem + T1OFF);
#pragma unroll
        for (int j = 0; j < 4; ++j) T1[(rb + j) * 16 + col] = g1[j];
      }
    }
    __syncthreads();  // SYNC2
    if (wave == 0) {
      float hv[4];
      cell_update(smem, g1, bt0_l1, bgb1, bob1, c1r, hv, lane);
      float* BNC = (float*)(smem + BNCOFF);
      if (is_act) {
#pragma unroll
        for (int j = 0; j < 4; ++j) BNC[(rb + j) * 8 + cs] = hv[j];
      }
      asm volatile("s_waitcnt lgkmcnt(0)" ::: "memory");
      float4 v0 = {0, 0, 0, 0}, v1 = {0, 0, 0, 0};
      if (lane < 16) {
        const int row = bg * 16 + lane;
        v0 = *(float4*)(BNC + lane * 8);
        v1 = *(float4*)(BNC + lane * 8 + 4);
        bf16x8 hi = pack8(v0, v1);
        unsigned short* base = h1buf + (size_t)(pp ^ 1) * 2 * BH;
        g_store16(base + (size_t)row * HID + u0, hi);
        bf16x8 lo;  // residual for the BL matmul (w_t row norms ~5.4 amplify h1 error)
        const float* va = (const float*)&v0;
        const float* vb = (const float*)&v1;
#pragma unroll
        for (int q = 0; q < 8; ++q) {
          const float f = (q < 4) ? va[q] : vb[q - 4];
          lo[q] = f2b(f - b2f(hi[q]));
        }
        g_store16(base + BH + (size_t)row * HID + u0, lo);
      }
      if (lane == 0) post_flag(myflag, tb + 3u);
      if (lane < 16) {  // d_out write AFTER the flag (off the critical path)
        const int row = bg * 16 + lane;
        float* od = out + ((size_t)t * BATCH + row) * HID + u0;
        *(float4*)od = v0;
        *(float4*)(od + 4) = v1;
      }
    }

    // ============== PHASE 2: x_{t+1} = h1 @ w_t^T + b_t ==============
    if (t + 1 < T_STEPS) {
      if (wave == 0) {
        poll_flags(cohort, tb + 3u);
        bf16x8 ahi[16], alo[16];
        const unsigned short* hb =
            h1buf + (size_t)(pp ^ 1) * 2 * BH + (size_t)arow * HID + koff;
        llc_load_frag_sync(ahi, hb);
        llc_load_frag_sync(alo, hb + BH);
        f32x4 A0 = {0, 0, 0, 0}, A1 = {0, 0, 0, 0};
        // B-tile: rows 0..7 = w_t buffer [pp], rows 8..15 = shared zero pad
        const unsigned int bb = (col < 8)
            ? (WSTOFF + (unsigned int)pp * 8192u + (unsigned int)col * 1024u)
            : (ZPADOFF + (unsigned int)(col - 8) * 1024u);
        const unsigned int sw = (unsigned int)(col & 7) << 4;
#pragma unroll
        for (int ks = 0; ks < 16; ++ks) {
          bf16x8 b =
              *(const bf16x8*)(smem + ((bb + (unsigned int)((ks * 32 + koff) * 2)) ^ sw));
          A0 = __builtin_amdgcn_mfma_f32_16x16x32_bf16(ahi[ks], b, A0, 0, 0, 0);
          A1 = __builtin_amdgcn_mfma_f32_16x16x32_bf16(alo[ks], b, A1, 0, 0, 0);
        }
        const float ebv = is_act ? ((const float*)(smem + EBOFF + pp * 32))[cs] : 0.f;
        const float xb = bmu_l + bsg_l * ebv;
        f32x4 a2 = A0 + A1;
        float* BNC = (float*)(smem + BNCOFF);
        if (is_act) {
#pragma unroll
          for (int j = 0; j < 4; ++j) BNC[(rb + j) * 8 + cs] = a2[j] + xb;
        }
        asm volatile("s_waitcnt lgkmcnt(0)" ::: "memory");
        if (lane < 16) {
          const int row = bg * 16 + lane;
          float4 v0 = *(float4*)(BNC + lane * 8);
          float4 v1 = *(float4*)(BNC + lane * 8 + 4);
          g_store16(xbuf + (size_t)(pp ^ 1) * BH + (size_t)row * HID + u0, pack8(v0, v1));
        }
        if (lane == 0) post_flag(myflag, tb + 4u);
      }
      // no trailing barrier: w_t/eps_b are double-buffered; SYNC1/SYNC2 order
      // wstage writes against phase-2 reads within each step.
    }
  }
}

extern "C" void kernel_launch(void* const* d_in, const int* in_sizes, int n_in, void* d_out,
                              int out_size, void* d_ws, size_t ws_size, hipStream_t stream) {
  const float* init_h = (const float*)d_in[1];
  const float* init_c = (const float*)d_in[2];
  const float* eps_w = (const float*)d_in[3];
  const float* eps_b = (const float*)d_in[4];
  const float* W_ih0 = (const float*)d_in[5];
  const float* W_hh0 = (const float*)d_in[6];
  const float* b_ih0 = (const float*)d_in[7];
  const float* b_hh0 = (const float*)d_in[8];
  const float* W_ih1 = (const float*)d_in[9];
  const float* W_hh1 = (const float*)d_in[10];
  const float* b_ih1 = (const float*)d_in[11];
  const float* b_hh1 = (const float*)d_in[12];
  const float* w_mu = (const float*)d_in[13];
  const float* w_log_var = (const float*)d_in[14];
  const float* b_mu = (const float*)d_in[15];
  const float* b_log_var = (const float*)d_in[16];
  float* out = (float*)d_out;

  unsigned char* ws = (unsigned char*)d_ws;
  unsigned int* flags = (unsigned int*)ws;                          // 4 cohorts * 1KB
  unsigned short* xbuf = (unsigned short*)(ws + 131072);            // 2 parity * 64*512 bf16
  unsigned short* h0buf = (unsigned short*)(ws + 262144);           // 2 parity
  unsigned short* h1buf = (unsigned short*)(ws + 393216);           // 2 parity * {hi,lo}

  hipMemsetAsync(flags, 0, 4 * 256 * sizeof(unsigned int), stream);
  hipFuncSetAttribute((const void*)dlstm_kernel, hipFuncAttributeMaxDynamicSharedMemorySize,
                      SMEM_BYTES);

  void* args[] = {(void*)&init_h, (void*)&init_c, (void*)&eps_w,  (void*)&eps_b,
                  (void*)&W_ih0,  (void*)&W_hh0,  (void*)&b_ih0,  (void*)&b_hh0,
                  (void*)&W_ih1,  (void*)&W_hh1,  (void*)&b_ih1,  (void*)&b_hh1,
                  (void*)&w_mu,   (void*)&w_log_var, (void*)&b_mu, (void*)&b_log_var,
                  (void*)&out,    (void*)&flags,     (void*)&xbuf, (void*)&h0buf,
                  (void*)&h1buf};
  hipError_t err = hipLaunchCooperativeKernel((void*)dlstm_kernel, dim3(NWG), dim3(NTHR), args,
                                              SMEM_BYTES, stream);
  if (err != hipSuccess) {
    // fallback: plain launch (256 WGs at 1/CU on 256 CUs are co-resident by capacity)
    hipLaunchKernelGGL(dlstm_kernel, dim3(NWG), dim3(NTHR), SMEM_BYTES, stream, init_h, init_c,
                       eps_w, eps_b, W_ih0, W_hh0, b_ih0, b_hh0, W_ih1, W_hh1, b_ih1, b_hh1,
                       w_mu, w_log_var, b_mu, b_log_var, out, flags, xbuf, h0buf, h1buf);
  }
}